// Round 6
// baseline (1907.838 us; speedup 1.0000x reference)
//
#include <hip/hip_runtime.h>

#define DI __device__ __forceinline__

typedef _Float16 f16_t;
typedef _Float16 f16x8 __attribute__((ext_vector_type(8)));
typedef float    f32x4 __attribute__((ext_vector_type(4)));

static_assert(sizeof(f16x8) == 16, "f16x8 must be 16B");

#define B_  16
#define C_  256
#define CH_ 128
#define N_  2048

DI f32x4 fzero(){ f32x4 z = {0.f,0.f,0.f,0.f}; return z; }
DI f16x8 ldg8(const f16_t* p){ return *(const f16x8*)p; }
DI f32x4 mfma16(f16x8 a, f16x8 b, f32x4 c){
  return __builtin_amdgcn_mfma_f32_16x16x32_f16(a, b, c, 0, 0, 0);
}
DI void split2(float v, f16_t& hi, f16_t& lo){
  hi = (f16_t)v; lo = (f16_t)(v - (float)hi);
}

// ---------------------------------------------------------------------------
// Weight fp32 -> fp16 hi/lo split pack. Per layer: WqS[128][512] WkS[128][512]
// WvS[256][512] WtS[256][512] (cols 0..255 = hi, 256..511 = lo).
__global__ void k_wconv(const float* q1,const float* k1,const float* v1,const float* t1,
                        const float* q2,const float* k2,const float* v2,const float* t2,
                        f16_t* out){
  int i = blockIdx.x*256 + threadIdx.x;            // 0..393215
  int l = (i >= 196608) ? 1 : 0;
  int r = i - l*196608;
  const float* s; long dbase;
  if(r < 32768){ s = l? q2:q1; dbase = 0; }
  else if(r < 65536){ r -= 32768; s = l? k2:k1; dbase = 65536; }
  else if(r < 131072){ r -= 65536; s = l? v2:v1; dbase = 131072; }
  else { r -= 131072; s = l? t2:t1; dbase = 262144; }
  int o = r >> 8, c = r & 255;
  float v = s[o*256 + c];
  f16_t hi, lo; split2(v, hi, lo);
  f16_t* d = out + (long)l*393216 + dbase + (long)o*512;
  d[c] = hi; d[c+256] = lo;
}

// ---------------------------------------------------------------------------
// Transpose+split: XtS[b][n][512] = {hi(x[b][:,n]), lo}. grid (B, N/32, C/64)
__global__ void k_transpose(const float* __restrict__ X, long bstride,
                            f16_t* __restrict__ XtS){
  int b = blockIdx.x, n0 = blockIdx.y*32, c0 = blockIdx.z*64;
  __shared__ float tl[32][65];
  int t = threadIdx.x;
  int nn = t & 31, cr = t >> 5;                     // cr in 0..7
  const float* src = X + (long)b*bstride + n0 + nn;
  #pragma unroll
  for(int i=0;i<8;i++){
    int cc = cr + i*8;
    tl[nn][cc] = src[(long)(c0+cc)*N_];
  }
  __syncthreads();
  int n2 = t >> 3, cq = (t & 7)*8;
  __align__(16) f16_t hi8[8], lo8[8];
  #pragma unroll
  for(int j=0;j<8;j++) split2(tl[n2][cq+j], hi8[j], lo8[j]);
  f16_t* dst = XtS + ((long)b*N_ + n0 + n2)*512 + c0 + cq;
  *(f16x8*)dst         = *(f16x8*)hi8;
  *(f16x8*)(dst + 256) = *(f16x8*)lo8;
}

// ---------------------------------------------------------------------------
// 3-term split GEMM: out[row][col] = sum_k (Ah+Al)[row][k]*(Bh+Bl)[col][k]
// (drops Al*Bl). A,B rows are 512-wide hi|lo, K=256. 64x64 tile, 4 waves.
template<int SPLIT_OUT, int BIAS>
__global__ __launch_bounds__(256) void k_gemm3(
    const f16_t* __restrict__ A, long sA,
    const f16_t* __restrict__ Bt, long sB,
    f16_t* __restrict__ out, int ldo, long sO,
    const float* __restrict__ bias)
{
  int b = blockIdx.x;
  int m0 = blockIdx.y*64, n0 = blockIdx.z*64;
  int t = threadIdx.x, w = t>>6, l = t&63, lr = l&15, lg = l>>4;
  const f16_t* Ab = A + (long)b*sA + (long)(m0 + w*16 + lr)*512;
  const f16_t* Bb = Bt + (long)b*sB;
  f32x4 acc[4];
  #pragma unroll
  for(int i=0;i<4;i++) acc[i] = fzero();
  for(int k=0;k<256;k+=32){
    f16x8 ah = ldg8(Ab + k + lg*8);
    f16x8 al = ldg8(Ab + 256 + k + lg*8);
    #pragma unroll
    for(int ns=0;ns<4;ns++){
      const f16_t* brow = Bb + (long)(n0 + ns*16 + lr)*512;
      f16x8 bh = ldg8(brow + k + lg*8);
      f16x8 bl = ldg8(brow + 256 + k + lg*8);
      acc[ns] = mfma16(ah, bh, acc[ns]);
      acc[ns] = mfma16(ah, bl, acc[ns]);
      acc[ns] = mfma16(al, bh, acc[ns]);
    }
  }
  f16_t* ob = out + (long)b*sO;
  #pragma unroll
  for(int ns=0;ns<4;ns++){
    #pragma unroll
    for(int j=0;j<4;j++){
      int row = m0 + w*16 + lg*4 + j;
      int col = n0 + ns*16 + lr;
      float v = acc[ns][j];
      if(BIAS) v += bias[row];
      if(SPLIT_OUT){
        f16_t hi, lo; split2(v, hi, lo);
        ob[(long)row*ldo + col]       = hi;
        ob[(long)row*ldo + col + 128] = lo;
      } else {
        ob[(long)row*ldo + col] = (f16_t)v;
      }
    }
  }
}

// ---------------------------------------------------------------------------
// Pass 1: rowoff[b][n] = rowmax + ln(sum exp). 8 waves; group g = w>>2 handles
// m in [g*1024,(g+1)*1024); LDS merge at end. grid (B, N/64).
__global__ __launch_bounds__(512,4) void k_rowstats(
    const f16_t* __restrict__ xqS, const f16_t* __restrict__ xkS,
    float* __restrict__ rowoff)
{
  const int b = blockIdx.x, n0 = blockIdx.y*64;
  const int t = threadIdx.x, w = t>>6, l = t&63, lr = l&15, lg = l>>4;
  const int g = w>>2, wg = w&3;
  __shared__ float RS[256];                  // R[2][64] | S[2][64]
  const f16_t* qp = xqS + ((long)b*N_ + n0 + wg*16 + lr)*256;
  f16x8 bqh[4], bql[4];
  #pragma unroll
  for(int k=0;k<4;k++){
    bqh[k] = ldg8(qp + k*32 + lg*8);
    bql[k] = ldg8(qp + 128 + k*32 + lg*8);
  }
  const f16_t* kb = xkS + (long)b*N_*256;
  float rmax = -3e38f, rsum = 0.f;
  for(int m0=g*1024; m0<g*1024+1024; m0+=64){
    #pragma unroll
    for(int s=0;s<4;s++){
      const f16_t* kr = kb + (long)(m0 + s*16 + lr)*256;
      f16x8 ah[4], al_[4];
      #pragma unroll
      for(int k=0;k<4;k++){
        ah[k]  = ldg8(kr + k*32 + lg*8);
        al_[k] = ldg8(kr + 128 + k*32 + lg*8);
      }
      f32x4 a1 = fzero(), a2 = fzero(), a3 = fzero();   // 3 independent chains
      #pragma unroll
      for(int k=0;k<4;k++) a1 = mfma16(ah[k],  bqh[k], a1);
      #pragma unroll
      for(int k=0;k<4;k++) a2 = mfma16(ah[k],  bql[k], a2);
      #pragma unroll
      for(int k=0;k<4;k++) a3 = mfma16(al_[k], bqh[k], a3);
      f32x4 acc = (a1 + a2) + a3;
      float vm = fmaxf(fmaxf(acc[0],acc[1]), fmaxf(acc[2],acc[3]));
      float nm = fmaxf(rmax, vm);
      rsum = rsum*__expf(rmax-nm)
           + __expf(acc[0]-nm)+__expf(acc[1]-nm)+__expf(acc[2]-nm)+__expf(acc[3]-nm);
      rmax = nm;
    }
  }
  #pragma unroll
  for(int off=16; off<64; off<<=1){
    float om = __shfl_xor(rmax, off, 64);
    float os = __shfl_xor(rsum, off, 64);
    float nm = fmaxf(rmax, om);
    rsum = rsum*__expf(rmax-nm) + os*__expf(om-nm);
    rmax = nm;
  }
  if(lg==0){
    RS[g*64 + wg*16 + lr]       = rmax;
    RS[128 + g*64 + wg*16 + lr] = rsum;
  }
  __syncthreads();
  if(g==0 && lg==0){
    int idx = wg*16 + lr;
    float m0v = RS[idx],     m1v = RS[64+idx];
    float s0  = RS[128+idx], s1  = RS[192+idx];
    float mm = fmaxf(m0v, m1v);
    float ss = s0*__expf(m0v-mm) + s1*__expf(m1v-mm);
    rowoff[(long)b*N_ + n0 + idx] = mm + __logf(ss);
  }
}

// ---------------------------------------------------------------------------
// Pass 2 (flash-col, wave-local): swapped-operand energy with permuted q rows
// so each lane's 8 P values ARE its PV B-fragment (m = w*16+lr, n = lg*8..+7).
// No barriers / no LDS in the loop. Online per-column max (defer THR=8).
// Outputs NORMALIZED partial Yhat = Y/S (fp16) + S, CM. grid (B, 32, 2).
__global__ __launch_bounds__(256) void k_apply(
    const f16_t* __restrict__ xqS, const f16_t* __restrict__ xkS,
    const f16_t* __restrict__ xv, const float* __restrict__ rowoff,
    f16_t* __restrict__ Yp, float* __restrict__ SCp)
{
  const int b = blockIdx.x, mt = blockIdx.y, m0 = mt*64, z = blockIdx.z;
  const int t = threadIdx.x, w = t>>6, l = t&63, lr = l&15, lg = l>>4;
  __shared__ __align__(16) float ro_s[1024];
  {
    const float* rob = rowoff + (long)b*N_ + z*1024;
    *(f32x4*)(ro_s + t*4) = *(const f32x4*)(rob + t*4);
  }
  __syncthreads();

  const f16_t* akp = xkS + ((long)b*N_ + m0 + w*16 + lr)*256;
  f16x8 akh[4], akl[4];
  #pragma unroll
  for(int k=0;k<4;k++){
    akh[k] = ldg8(akp + k*32 + lg*8);
    akl[k] = ldg8(akp + 128 + k*32 + lg*8);
  }

  const f16_t* xqb = xqS + (long)b*N_*256;
  const f16_t* xvb = xv + (long)b*C_*N_ + (long)lr*N_;   // + cf*16 rows
  const int qperm = ((lr>>2)*8 + (lr&3));                // + s2*4

  f32x4 y[16];
  #pragma unroll
  for(int i=0;i<16;i++) y[i] = fzero();
  float cs = 0.f, cm = -3e38f;

  #pragma unroll 1
  for(int n0l=0; n0l<1024; n0l+=32){
    const int n0 = z*1024 + n0l;
    // energies -> g[s2][j] = e[n = n0+lg*8+s2*4+j][m = m0+w*16+lr] - ro[n]
    float g[2][4];
    #pragma unroll
    for(int s2=0;s2<2;s2++){
      const f16_t* qr = xqb + (long)(n0 + qperm + s2*4)*256;
      f16x8 qh[4], ql[4];
      #pragma unroll
      for(int k=0;k<4;k++){
        qh[k] = ldg8(qr + k*32 + lg*8);
        ql[k] = ldg8(qr + 128 + k*32 + lg*8);
      }
      f32x4 e1 = fzero(), e2 = fzero(), e3 = fzero();
      #pragma unroll
      for(int k=0;k<4;k++) e1 = mfma16(qh[k], akh[k], e1);
      #pragma unroll
      for(int k=0;k<4;k++) e2 = mfma16(ql[k], akh[k], e2);
      #pragma unroll
      for(int k=0;k<4;k++) e3 = mfma16(qh[k], akl[k], e3);
      f32x4 e = (e1 + e2) + e3;
      f32x4 ro4 = *(const f32x4*)(ro_s + n0l + lg*8 + s2*4);
      #pragma unroll
      for(int j=0;j<4;j++) g[s2][j] = e[j] - ro4[j];
    }
    // per-column (m=lr) chunk max over the 32 n's: in-lane 8, then lg-groups
    float v = fmaxf(fmaxf(fmaxf(g[0][0],g[0][1]), fmaxf(g[0][2],g[0][3])),
                    fmaxf(fmaxf(g[1][0],g[1][1]), fmaxf(g[1][2],g[1][3])));
    v = fmaxf(v, __shfl_xor(v, 16, 64));
    v = fmaxf(v, __shfl_xor(v, 32, 64));
    bool need = v > cm + 8.f;
    float fj = need ? __expf(cm - v) : 1.f;
    if(need) cm = v;
    cs *= fj;
    // P (fp16) in-register = PV B-frag; colsum from the SAME rounded values
    __align__(16) f16_t pv[8];
    #pragma unroll
    for(int s2=0;s2<2;s2++){
      #pragma unroll
      for(int j=0;j<4;j++){
        float p = __expf(g[s2][j] - cm);
        f16_t pb = (f16_t)p;
        cs += (float)pb;
        pv[s2*4+j] = pb;
      }
    }
    f16x8 pfrag = *(const f16x8*)pv;
    if(__any(need)){
      #pragma unroll
      for(int cf=0;cf<16;cf++){
        #pragma unroll
        for(int j2=0;j2<4;j2++) y[cf][j2] *= fj;
      }
    }
    // PV: y[cf] covers c = cf*16 + lg*4 + j, m = lr (col)
    #pragma unroll
    for(int cf=0;cf<16;cf++){
      f16x8 av = ldg8(xvb + (long)cf*16*N_ + n0 + lg*8);
      y[cf] = mfma16(av, pfrag, y[cf]);
    }
  }

  // colsum: sum partials over the 4 lg lane-groups (butterfly -> all lanes)
  cs += __shfl_xor(cs, 16, 64);
  cs += __shfl_xor(cs, 32, 64);
  if(lg==0){
    SCp[((long)(z*2+0)*B_ + b)*N_ + m0 + w*16 + lr] = cs;
    SCp[((long)(z*2+1)*B_ + b)*N_ + m0 + w*16 + lr] = cm;
  }
  float invl = 1.f/cs;                         // S >= ~1
  f16_t* yb = Yp + (((long)z*B_ + b)*32 + mt)*16384;
  #pragma unroll
  for(int cf=0;cf<16;cf++){
    #pragma unroll
    for(int j=0;j<4;j++){
      int c = cf*16 + lg*4 + j;
      yb[(long)c*64 + w*16 + lr] = (f16_t)(y[cf][j]*invl);
    }
  }
}

// ---------------------------------------------------------------------------
// Merge the two n-splits + h0 epilogue: x_r = (Y0*w0+Y1*w1)/(1e-9*e^-cf+w0+w1),
// h0 = X - x_r -> h0T fp16. grid (B, 32).
__global__ __launch_bounds__(256) void k_merge(
    const f16_t* __restrict__ Yp, const float* __restrict__ SCp,
    const float* __restrict__ X, long xbstride, f16_t* __restrict__ h0T)
{
  const int b = blockIdx.x, mt = blockIdx.y, m0 = mt*64;
  const int t = threadIdx.x, mq = t&63, cq = t>>6;
  __shared__ __align__(16) char smem[32768];
  f16_t* H = (f16_t*)smem;                     // swizzled [64][256]
  float s0 = SCp[((long)0*B_+b)*N_ + m0 + mq];
  float c0 = SCp[((long)1*B_+b)*N_ + m0 + mq];
  float s1 = SCp[((long)2*B_+b)*N_ + m0 + mq];
  float c1 = SCp[((long)3*B_+b)*N_ + m0 + mq];
  float cf = fmaxf(c0, c1);
  float w0 = s0*__expf(c0-cf), w1 = s1*__expf(c1-cf);
  float invd = 1.f/(1e-9f*__expf(-cf) + w0 + w1);
  w0 *= invd; w1 *= invd;
  const f16_t* y0 = Yp + (((long)0*B_ + b)*32 + mt)*16384;
  const f16_t* y1 = Yp + (((long)1*B_ + b)*32 + mt)*16384;
  const float* Xb = X + (long)b*xbstride + m0;
  #pragma unroll 4
  for(int ci=0; ci<64; ci++){
    int c = cq*64 + ci;
    float yv = (float)y0[(long)c*64 + mq]*w0 + (float)y1[(long)c*64 + mq]*w1;
    float h0v = Xb[(long)c*N_ + mq] - yv;
    *(f16_t*)((char*)H + mq*512 + ((((c>>3) ^ (mq&7))<<4) | ((c&7)<<1))) = (f16_t)h0v;
  }
  __syncthreads();
  uint4* dst = (uint4*)(h0T + ((long)b*N_ + m0)*C_);
  const uint4* src = (const uint4*)H;
  for(int i=t;i<2048;i+=256){
    int row = i>>5, slot = i&31;
    dst[i] = src[(i & ~31) | (slot ^ (row&7))];
  }
}

// ---------------------------------------------------------------------------
// h1[b][o][m] = Wt @ h0 + bt (2-term: Wt hi+lo), fp16 out + BN partial sums.
__global__ __launch_bounds__(256) void k_wt_bn(
    const f16_t* __restrict__ WtS, const f16_t* __restrict__ h0T,
    const float* __restrict__ bt,
    f16_t* __restrict__ h1, float* __restrict__ bnacc)
{
  int b = blockIdx.x, o0 = blockIdx.y*64, m0 = blockIdx.z*64;
  int t=threadIdx.x, w=t>>6, l=t&63, lr=l&15, lg=l>>4;
  const f16_t* Arow = WtS + (long)(o0 + w*16 + lr)*512;
  const f16_t* Bb = h0T + (long)b*N_*C_;
  f32x4 acc[4];
  #pragma unroll
  for(int i=0;i<4;i++) acc[i] = fzero();
  for(int k=0;k<C_;k+=32){
    f16x8 afh = ldg8(Arow + k + lg*8);
    f16x8 afl = ldg8(Arow + 256 + k + lg*8);
    #pragma unroll
    for(int ms=0;ms<4;ms++){
      f16x8 bf_ = ldg8(Bb + (long)(m0 + ms*16 + lr)*C_ + k + lg*8);
      acc[ms] = mfma16(afh, bf_, acc[ms]);
      acc[ms] = mfma16(afl, bf_, acc[ms]);
    }
  }
  float s1[4]={0.f,0.f,0.f,0.f}, s2v[4]={0.f,0.f,0.f,0.f};
  f16_t* h1b = h1 + (long)b*C_*N_;
  #pragma unroll
  for(int j=0;j<4;j++){
    int o = o0 + w*16 + lg*4 + j;
    float bias = bt[o];
    #pragma unroll
    for(int ms=0;ms<4;ms++){
      float v = acc[ms][j] + bias;
      h1b[(long)o*N_ + m0 + ms*16 + lr] = (f16_t)v;
      s1[j] += v; s2v[j] += v*v;
    }
  }
  #pragma unroll
  for(int off=1; off<16; off<<=1){
    #pragma unroll
    for(int j=0;j<4;j++){ s1[j]+=__shfl_xor(s1[j],off,64); s2v[j]+=__shfl_xor(s2v[j],off,64); }
  }
  if(lr==0){
    #pragma unroll
    for(int j=0;j<4;j++){
      int o = o0 + w*16 + lg*4 + j;
      atomicAdd(&bnacc[o], s1[j]);
      atomicAdd(&bnacc[256+o], s2v[j]);
    }
  }
}

// BN finalize -> scale/shift
__global__ void k_bnfin(const float* __restrict__ bnacc, const float* __restrict__ gamma,
                        const float* __restrict__ beta, float* __restrict__ scsh){
  int o = threadIdx.x;
  float mean = bnacc[o] * (1.f/32768.f);
  float var  = bnacc[256+o] * (1.f/32768.f) - mean*mean;
  float sc = gamma[o] * rsqrtf(var + 1e-5f);
  scsh[o] = sc;
  scsh[256+o] = beta[o] - mean*sc;
}

// out = X + relu(h1*sc + sh); writes one 256-channel half of d_out. 8 elems/thr.
__global__ void k_out(const f16_t* __restrict__ h1, const float* __restrict__ X, long xbstride,
                      const float* __restrict__ scsh, float* __restrict__ out, long ocoff){
  long i = (long)blockIdx.x*256 + threadIdx.x;  // 1,048,576 threads
  long e = i*8;
  int b = (int)(e >> 19);
  int rem = (int)(e & 524287);                  // c*2048 + m
  int c = rem >> 11;
  f16x8 hv = *(const f16x8*)(h1 + e);
  const float* xb = X + (long)b*xbstride + rem;
  float4 xr0 = *(const float4*)xb;
  float4 xr1 = *(const float4*)(xb + 4);
  float sc = scsh[c], sh = scsh[256+c];
  float4 o0, o1;
  o0.x = xr0.x + fmaxf(fmaf((float)hv[0], sc, sh), 0.f);
  o0.y = xr0.y + fmaxf(fmaf((float)hv[1], sc, sh), 0.f);
  o0.z = xr0.z + fmaxf(fmaf((float)hv[2], sc, sh), 0.f);
  o0.w = xr0.w + fmaxf(fmaf((float)hv[3], sc, sh), 0.f);
  o1.x = xr1.x + fmaxf(fmaf((float)hv[4], sc, sh), 0.f);
  o1.y = xr1.y + fmaxf(fmaf((float)hv[5], sc, sh), 0.f);
  o1.z = xr1.z + fmaxf(fmaf((float)hv[6], sc, sh), 0.f);
  o1.w = xr1.w + fmaxf(fmaf((float)hv[7], sc, sh), 0.f);
  float* ob = out + (long)b*(512L*N_) + ocoff + rem;
  *(float4*)ob       = o0;
  *(float4*)(ob + 4) = o1;
}

// ---------------------------------------------------------------------------
extern "C" void kernel_launch(void* const* d_in, const int* in_sizes, int n_in,
                              void* d_out, int out_size, void* d_ws, size_t ws_size,
                              hipStream_t stream){
  (void)in_sizes; (void)n_in; (void)out_size; (void)ws_size;
  const float* x = (const float*)d_in[0];
  const float *Wf[2][4], *bv[2], *bt[2], *gm[2], *bb[2];
  for(int l=0;l<2;l++){
    int base = 1 + l*8;
    Wf[l][0]=(const float*)d_in[base+0];  // Wq
    Wf[l][1]=(const float*)d_in[base+1];  // Wk
    Wf[l][2]=(const float*)d_in[base+2];  // Wv
    bv[l]   =(const float*)d_in[base+3];
    Wf[l][3]=(const float*)d_in[base+4];  // Wt
    bt[l]   =(const float*)d_in[base+5];
    gm[l]   =(const float*)d_in[base+6];
    bb[l]   =(const float*)d_in[base+7];
  }
  char* ws = (char*)d_ws;
  size_t off = 0;
  auto alloc = [&](size_t bytes){ size_t o = off; off += (bytes + 255) & ~(size_t)255; return o; };
  size_t oXt = alloc((size_t)B_*N_*512*2);     // fp16 split x^T (33.5MB; Yp aliases)
  size_t oXq = alloc((size_t)B_*N_*256*2);     // fp16 split q [n][256]
  size_t oXk = alloc((size_t)B_*N_*256*2);     // fp16 split k [m][256]
  size_t oXv = alloc((size_t)B_*C_*N_*2);      // fp16 v [c][n]
  size_t oH0 = alloc((size_t)B_*N_*C_*2);      // fp16 h0^T [m][c]
  size_t oRo = alloc((size_t)B_*N_*4);         // f32 rowoff
  size_t oSC = alloc((size_t)4*B_*N_*4);       // f32 S/CM partials (z,{S,CM})
  size_t oBn = alloc(2*512*4);                 // BN accum per layer
  size_t oSc = alloc(2*512*4);                 // BN scale/shift per layer
  size_t oW  = alloc((size_t)786432*2);        // fp16 split weights

  hipMemsetAsync(ws + oBn, 0, 2*512*4, stream);
  k_wconv<<<1536,256,0,stream>>>(Wf[0][0],Wf[0][1],Wf[0][2],Wf[0][3],
                                 Wf[1][0],Wf[1][1],Wf[1][2],Wf[1][3],
                                 (f16_t*)(ws+oW));
  float* dout = (float*)d_out;
  f16_t* H1 = (f16_t*)(ws + oXq);              // aliases Xq (dead when used)
  for(int l=0;l<2;l++){
    const float* Xl = l ? dout : x;
    long xbs = l ? 512L*N_ : 256L*N_;
    const f16_t* WqS = (const f16_t*)(ws+oW) + (size_t)l*393216;
    const f16_t* WkS = WqS + 65536;
    const f16_t* WvS = WqS + 131072;
    const f16_t* WtS = WqS + 262144;
    f16_t* XtS = (f16_t*)(ws+oXt);
    f16_t* Yp  = (f16_t*)(ws+oXt);             // aliases XtS (dead after gemms)
    f16_t* Xq  = (f16_t*)(ws+oXq);
    f16_t* Xk  = (f16_t*)(ws+oXk);
    f16_t* Xv  = (f16_t*)(ws+oXv);
    f16_t* H0  = (f16_t*)(ws+oH0);
    float* Ro  = (float*)(ws+oRo);
    float* SCp = (float*)(ws+oSC);
    float* Bn  = (float*)(ws+oBn) + l*512;
    float* Sc  = (float*)(ws+oSc) + l*512;

    k_transpose<<<dim3(B_, N_/32, C_/64),256,0,stream>>>(Xl, xbs, XtS);
    k_gemm3<1,0><<<dim3(B_,32,2),256,0,stream>>>(XtS, (long)N_*512, WqS, 0L,
                                                 Xq, 256, (long)N_*256, nullptr);
    k_gemm3<1,0><<<dim3(B_,32,2),256,0,stream>>>(XtS, (long)N_*512, WkS, 0L,
                                                 Xk, 256, (long)N_*256, nullptr);
    k_gemm3<0,1><<<dim3(B_,4,32),256,0,stream>>>(WvS, 0L, XtS, (long)N_*512,
                                                 Xv, N_, (long)C_*N_, bv[l]);
    k_rowstats<<<dim3(B_, N_/64),512,0,stream>>>(Xq, Xk, Ro);
    k_apply<<<dim3(B_, 32, 2),256,0,stream>>>(Xq, Xk, Xv, Ro, Yp, SCp);
    k_merge<<<dim3(B_, 32),256,0,stream>>>(Yp, SCp, Xl, xbs, H0);
    k_wt_bn<<<dim3(B_,4,32),256,0,stream>>>(WtS, H0, bt[l], H1, Bn);
    k_bnfin<<<1,256,0,stream>>>(Bn, gm[l], bb[l], Sc);
    k_out<<<4096,256,0,stream>>>(H1, Xl, xbs, Sc, dout, (long)l*C_*N_);
  }
}

// Round 7
// 1901.819 us; speedup vs baseline: 1.0032x; 1.0032x over previous
//
#include <hip/hip_runtime.h>

#define DI __device__ __forceinline__

typedef _Float16 f16_t;
typedef _Float16 f16x8 __attribute__((ext_vector_type(8)));
typedef float    f32x4 __attribute__((ext_vector_type(4)));

static_assert(sizeof(f16x8) == 16, "f16x8 must be 16B");

#define B_  16
#define C_  256
#define CH_ 128
#define N_  2048

DI f32x4 fzero(){ f32x4 z = {0.f,0.f,0.f,0.f}; return z; }
DI f16x8 ldg8(const f16_t* p){ return *(const f16x8*)p; }
DI f32x4 mfma16(f16x8 a, f16x8 b, f32x4 c){
  return __builtin_amdgcn_mfma_f32_16x16x32_f16(a, b, c, 0, 0, 0);
}
DI void split2(float v, f16_t& hi, f16_t& lo){
  hi = (f16_t)v; lo = (f16_t)(v - (float)hi);
}

// ---------------------------------------------------------------------------
// Weight fp32 -> fp16 hi/lo split pack. Per layer: WqS[128][512] WkS[128][512]
// WvS[256][512] WtS[256][512] (cols 0..255 = hi, 256..511 = lo).
__global__ void k_wconv(const float* q1,const float* k1,const float* v1,const float* t1,
                        const float* q2,const float* k2,const float* v2,const float* t2,
                        f16_t* out){
  int i = blockIdx.x*256 + threadIdx.x;            // 0..393215
  int l = (i >= 196608) ? 1 : 0;
  int r = i - l*196608;
  const float* s; long dbase;
  if(r < 32768){ s = l? q2:q1; dbase = 0; }
  else if(r < 65536){ r -= 32768; s = l? k2:k1; dbase = 65536; }
  else if(r < 131072){ r -= 65536; s = l? v2:v1; dbase = 131072; }
  else { r -= 131072; s = l? t2:t1; dbase = 262144; }
  int o = r >> 8, c = r & 255;
  float v = s[o*256 + c];
  f16_t hi, lo; split2(v, hi, lo);
  f16_t* d = out + (long)l*393216 + dbase + (long)o*512;
  d[c] = hi; d[c+256] = lo;
}

// ---------------------------------------------------------------------------
// Transpose+split: XtS[b][n][512] = {hi(x[b][:,n]), lo}. grid (B, N/32, C/64)
__global__ void k_transpose(const float* __restrict__ X, long bstride,
                            f16_t* __restrict__ XtS){
  int b = blockIdx.x, n0 = blockIdx.y*32, c0 = blockIdx.z*64;
  __shared__ float tl[32][65];
  int t = threadIdx.x;
  int nn = t & 31, cr = t >> 5;                     // cr in 0..7
  const float* src = X + (long)b*bstride + n0 + nn;
  #pragma unroll
  for(int i=0;i<8;i++){
    int cc = cr + i*8;
    tl[nn][cc] = src[(long)(c0+cc)*N_];
  }
  __syncthreads();
  int n2 = t >> 3, cq = (t & 7)*8;
  __align__(16) f16_t hi8[8], lo8[8];
  #pragma unroll
  for(int j=0;j<8;j++) split2(tl[n2][cq+j], hi8[j], lo8[j]);
  f16_t* dst = XtS + ((long)b*N_ + n0 + n2)*512 + c0 + cq;
  *(f16x8*)dst         = *(f16x8*)hi8;
  *(f16x8*)(dst + 256) = *(f16x8*)lo8;
}

// ---------------------------------------------------------------------------
// 3-term split GEMM: out[row][col] = sum_k (Ah+Al)[row][k]*(Bh+Bl)[col][k]
// (drops Al*Bl). A,B rows are 512-wide hi|lo, K=256. 64x64 tile, 4 waves.
template<int SPLIT_OUT, int BIAS>
__global__ __launch_bounds__(256) void k_gemm3(
    const f16_t* __restrict__ A, long sA,
    const f16_t* __restrict__ Bt, long sB,
    f16_t* __restrict__ out, int ldo, long sO,
    const float* __restrict__ bias)
{
  int b = blockIdx.x;
  int m0 = blockIdx.y*64, n0 = blockIdx.z*64;
  int t = threadIdx.x, w = t>>6, l = t&63, lr = l&15, lg = l>>4;
  const f16_t* Ab = A + (long)b*sA + (long)(m0 + w*16 + lr)*512;
  const f16_t* Bb = Bt + (long)b*sB;
  f32x4 acc[4];
  #pragma unroll
  for(int i=0;i<4;i++) acc[i] = fzero();
  for(int k=0;k<256;k+=32){
    f16x8 ah = ldg8(Ab + k + lg*8);
    f16x8 al = ldg8(Ab + 256 + k + lg*8);
    #pragma unroll
    for(int ns=0;ns<4;ns++){
      const f16_t* brow = Bb + (long)(n0 + ns*16 + lr)*512;
      f16x8 bh = ldg8(brow + k + lg*8);
      f16x8 bl = ldg8(brow + 256 + k + lg*8);
      acc[ns] = mfma16(ah, bh, acc[ns]);
      acc[ns] = mfma16(ah, bl, acc[ns]);
      acc[ns] = mfma16(al, bh, acc[ns]);
    }
  }
  f16_t* ob = out + (long)b*sO;
  #pragma unroll
  for(int ns=0;ns<4;ns++){
    #pragma unroll
    for(int j=0;j<4;j++){
      int row = m0 + w*16 + lg*4 + j;
      int col = n0 + ns*16 + lr;
      float v = acc[ns][j];
      if(BIAS) v += bias[row];
      if(SPLIT_OUT){
        f16_t hi, lo; split2(v, hi, lo);
        ob[(long)row*ldo + col]       = hi;
        ob[(long)row*ldo + col + 128] = lo;
      } else {
        ob[(long)row*ldo + col] = (f16_t)v;
      }
    }
  }
}

// ---------------------------------------------------------------------------
// Pass 1: rowoff[b][n] = rowmax + ln(sum exp). 8 waves; group g = w>>2 handles
// m in [g*1024,(g+1)*1024); LDS merge at end. grid (B, N/64).
__global__ __launch_bounds__(512,4) void k_rowstats(
    const f16_t* __restrict__ xqS, const f16_t* __restrict__ xkS,
    float* __restrict__ rowoff)
{
  const int b = blockIdx.x, n0 = blockIdx.y*64;
  const int t = threadIdx.x, w = t>>6, l = t&63, lr = l&15, lg = l>>4;
  const int g = w>>2, wg = w&3;
  __shared__ float RS[256];                  // R[2][64] | S[2][64]
  const f16_t* qp = xqS + ((long)b*N_ + n0 + wg*16 + lr)*256;
  f16x8 bqh[4], bql[4];
  #pragma unroll
  for(int k=0;k<4;k++){
    bqh[k] = ldg8(qp + k*32 + lg*8);
    bql[k] = ldg8(qp + 128 + k*32 + lg*8);
  }
  const f16_t* kb = xkS + (long)b*N_*256;
  float rmax = -3e38f, rsum = 0.f;
  for(int m0=g*1024; m0<g*1024+1024; m0+=64){
    #pragma unroll
    for(int s=0;s<4;s++){
      const f16_t* kr = kb + (long)(m0 + s*16 + lr)*256;
      f16x8 ah[4], al_[4];
      #pragma unroll
      for(int k=0;k<4;k++){
        ah[k]  = ldg8(kr + k*32 + lg*8);
        al_[k] = ldg8(kr + 128 + k*32 + lg*8);
      }
      f32x4 a1 = fzero(), a2 = fzero(), a3 = fzero();   // 3 independent chains
      #pragma unroll
      for(int k=0;k<4;k++) a1 = mfma16(ah[k],  bqh[k], a1);
      #pragma unroll
      for(int k=0;k<4;k++) a2 = mfma16(ah[k],  bql[k], a2);
      #pragma unroll
      for(int k=0;k<4;k++) a3 = mfma16(al_[k], bqh[k], a3);
      f32x4 acc = (a1 + a2) + a3;
      float vm = fmaxf(fmaxf(acc[0],acc[1]), fmaxf(acc[2],acc[3]));
      float nm = fmaxf(rmax, vm);
      rsum = rsum*__expf(rmax-nm)
           + __expf(acc[0]-nm)+__expf(acc[1]-nm)+__expf(acc[2]-nm)+__expf(acc[3]-nm);
      rmax = nm;
    }
  }
  #pragma unroll
  for(int off=16; off<64; off<<=1){
    float om = __shfl_xor(rmax, off, 64);
    float os = __shfl_xor(rsum, off, 64);
    float nm = fmaxf(rmax, om);
    rsum = rsum*__expf(rmax-nm) + os*__expf(om-nm);
    rmax = nm;
  }
  if(lg==0){
    RS[g*64 + wg*16 + lr]       = rmax;
    RS[128 + g*64 + wg*16 + lr] = rsum;
  }
  __syncthreads();
  if(g==0 && lg==0){
    int idx = wg*16 + lr;
    float m0v = RS[idx],     m1v = RS[64+idx];
    float s0  = RS[128+idx], s1  = RS[192+idx];
    float mm = fmaxf(m0v, m1v);
    float ss = s0*__expf(m0v-mm) + s1*__expf(m1v-mm);
    rowoff[(long)b*N_ + n0 + idx] = mm + __logf(ss);
  }
}

// ---------------------------------------------------------------------------
// Pass 2 (flash-col, wave-local, full n per block): swapped-operand energy with
// permuted q rows so each lane's 8 P values ARE its PV B-fragment
// (m = w*16+lr, n = lg*8..+7). V loads issued at the TOP of each chunk so
// their L2 latency hides under energy+softmax. Online per-column max (defer
// THR=8). Inline h0 epilogue (LDS transpose), writes h0T. grid (B, 32).
__global__ __launch_bounds__(256) void k_apply(
    const f16_t* __restrict__ xqS, const f16_t* __restrict__ xkS,
    const f16_t* __restrict__ xv, const float* __restrict__ rowoff,
    const float* __restrict__ X, long xbstride, f16_t* __restrict__ h0T)
{
  const int b = blockIdx.x, mt = blockIdx.y, m0 = mt*64;
  const int t = threadIdx.x, w = t>>6, l = t&63, lr = l&15, lg = l>>4;
  __shared__ __align__(16) char smem[40960];
  f16_t* H    = (f16_t*)smem;                  // 32KB swizzled [64][256] (epilogue)
  float* ro_s = (float*)(smem + 32768);        // 8KB rowoff cache
  {
    const float* rob = rowoff + (long)b*N_;
    *(f32x4*)(ro_s + t*4)        = *(const f32x4*)(rob + t*4);
    *(f32x4*)(ro_s + t*4 + 1024) = *(const f32x4*)(rob + t*4 + 1024);
  }
  __syncthreads();

  const f16_t* akp = xkS + ((long)b*N_ + m0 + w*16 + lr)*256;
  f16x8 akh[4], akl[4];
  #pragma unroll
  for(int k=0;k<4;k++){
    akh[k] = ldg8(akp + k*32 + lg*8);
    akl[k] = ldg8(akp + 128 + k*32 + lg*8);
  }

  const f16_t* xqb = xqS + (long)b*N_*256;
  const f16_t* xvb = xv + (long)b*C_*N_ + (long)lr*N_;   // + cf*16 rows
  const int qperm = ((lr>>2)*8 + (lr&3));                // + s2*4

  f32x4 y[16];
  #pragma unroll
  for(int i=0;i<16;i++) y[i] = fzero();
  float cs = 0.f, cm = -3e38f;

  #pragma unroll 1
  for(int n0=0; n0<N_; n0+=32){
    // ---- issue-early V loads (consumed at the end of the chunk) ----
    f16x8 av[16];
    #pragma unroll
    for(int cf=0;cf<16;cf++) av[cf] = ldg8(xvb + (long)cf*16*N_ + n0 + lg*8);
    // ---- energies -> g[s2][j] = e[n = n0+lg*8+s2*4+j][m = m0+w*16+lr] - ro[n]
    float g[2][4];
    #pragma unroll
    for(int s2=0;s2<2;s2++){
      const f16_t* qr = xqb + (long)(n0 + qperm + s2*4)*256;
      f16x8 qh[4], ql[4];
      #pragma unroll
      for(int k=0;k<4;k++){
        qh[k] = ldg8(qr + k*32 + lg*8);
        ql[k] = ldg8(qr + 128 + k*32 + lg*8);
      }
      f32x4 e1 = fzero(), e2 = fzero(), e3 = fzero();
      #pragma unroll
      for(int k=0;k<4;k++) e1 = mfma16(qh[k], akh[k], e1);
      #pragma unroll
      for(int k=0;k<4;k++) e2 = mfma16(ql[k], akh[k], e2);
      #pragma unroll
      for(int k=0;k<4;k++) e3 = mfma16(qh[k], akl[k], e3);
      f32x4 e = (e1 + e2) + e3;
      f32x4 ro4 = *(const f32x4*)(ro_s + n0 + lg*8 + s2*4);
      #pragma unroll
      for(int j=0;j<4;j++) g[s2][j] = e[j] - ro4[j];
    }
    // ---- per-column (m=lr) chunk max: in-lane 8, then 2 shfl across lg ----
    float v = fmaxf(fmaxf(fmaxf(g[0][0],g[0][1]), fmaxf(g[0][2],g[0][3])),
                    fmaxf(fmaxf(g[1][0],g[1][1]), fmaxf(g[1][2],g[1][3])));
    v = fmaxf(v, __shfl_xor(v, 16, 64));
    v = fmaxf(v, __shfl_xor(v, 32, 64));
    bool need = v > cm + 8.f;
    float fj = need ? __expf(cm - v) : 1.f;
    if(need) cm = v;
    cs *= fj;
    // ---- P (fp16) in-register = PV B-frag; colsum from SAME rounded values
    __align__(16) f16_t pv[8];
    #pragma unroll
    for(int s2=0;s2<2;s2++){
      #pragma unroll
      for(int j=0;j<4;j++){
        float p = __expf(g[s2][j] - cm);
        f16_t pb = (f16_t)p;
        cs += (float)pb;
        pv[s2*4+j] = pb;
      }
    }
    f16x8 pfrag = *(const f16x8*)pv;
    if(__any(need)){
      #pragma unroll
      for(int cf=0;cf<16;cf++){
        #pragma unroll
        for(int j2=0;j2<4;j2++) y[cf][j2] *= fj;
      }
    }
    // ---- PV: y[cf] covers c = cf*16 + lg*4 + j, m = lr (col) ----
    #pragma unroll
    for(int cf=0;cf<16;cf++) y[cf] = mfma16(av[cf], pfrag, y[cf]);
  }

  // colsum across the 4 lg lane-groups (butterfly -> all lanes)
  cs += __shfl_xor(cs, 16, 64);
  cs += __shfl_xor(cs, 32, 64);
  float inv = 1.f/(1e-9f*__expf(-cm) + cs);

  // ---- epilogue: x_r -> LDS (swizzled [m][c]), then h0 = X - x_r -> h0T ----
  #pragma unroll
  for(int cf=0;cf<16;cf++){
    #pragma unroll
    for(int j=0;j<4;j++){
      int c = cf*16 + lg*4 + j;
      int m = w*16 + lr;
      *(f16_t*)((char*)H + m*512 + ((((c>>3) ^ (m&7))<<4) | ((c&7)<<1)))
        = (f16_t)(y[cf][j]*inv);
    }
  }
  __syncthreads();
  {
    const int mq = t&63, cq = t>>6;
    const float* Xb = X + (long)b*xbstride + m0;
    #pragma unroll 4
    for(int ci=0; ci<64; ci++){
      int c = cq*64 + ci;
      f16_t* hp = (f16_t*)((char*)H + mq*512 + ((((c>>3) ^ (mq&7))<<4) | ((c&7)<<1)));
      float h0v = Xb[(long)c*N_ + mq] - (float)*hp;
      *hp = (f16_t)h0v;
    }
  }
  __syncthreads();
  {
    uint4* dst = (uint4*)(h0T + ((long)b*N_ + m0)*C_);
    const uint4* src = (const uint4*)H;
    for(int i=t;i<2048;i+=256){
      int row = i>>5, slot = i&31;
      dst[i] = src[(i & ~31) | (slot ^ (row&7))];
    }
  }
}

// ---------------------------------------------------------------------------
// h1[b][o][m] = Wt @ h0 + bt (2-term: Wt hi+lo), fp16 out + BN partial sums.
__global__ __launch_bounds__(256) void k_wt_bn(
    const f16_t* __restrict__ WtS, const f16_t* __restrict__ h0T,
    const float* __restrict__ bt,
    f16_t* __restrict__ h1, float* __restrict__ bnacc)
{
  int b = blockIdx.x, o0 = blockIdx.y*64, m0 = blockIdx.z*64;
  int t=threadIdx.x, w=t>>6, l=t&63, lr=l&15, lg=l>>4;
  const f16_t* Arow = WtS + (long)(o0 + w*16 + lr)*512;
  const f16_t* Bb = h0T + (long)b*N_*C_;
  f32x4 acc[4];
  #pragma unroll
  for(int i=0;i<4;i++) acc[i] = fzero();
  for(int k=0;k<C_;k+=32){
    f16x8 afh = ldg8(Arow + k + lg*8);
    f16x8 afl = ldg8(Arow + 256 + k + lg*8);
    #pragma unroll
    for(int ms=0;ms<4;ms++){
      f16x8 bf_ = ldg8(Bb + (long)(m0 + ms*16 + lr)*C_ + k + lg*8);
      acc[ms] = mfma16(afh, bf_, acc[ms]);
      acc[ms] = mfma16(afl, bf_, acc[ms]);
    }
  }
  float s1[4]={0.f,0.f,0.f,0.f}, s2v[4]={0.f,0.f,0.f,0.f};
  f16_t* h1b = h1 + (long)b*C_*N_;
  #pragma unroll
  for(int j=0;j<4;j++){
    int o = o0 + w*16 + lg*4 + j;
    float bias = bt[o];
    #pragma unroll
    for(int ms=0;ms<4;ms++){
      float v = acc[ms][j] + bias;
      h1b[(long)o*N_ + m0 + ms*16 + lr] = (f16_t)v;
      s1[j] += v; s2v[j] += v*v;
    }
  }
  #pragma unroll
  for(int off=1; off<16; off<<=1){
    #pragma unroll
    for(int j=0;j<4;j++){ s1[j]+=__shfl_xor(s1[j],off,64); s2v[j]+=__shfl_xor(s2v[j],off,64); }
  }
  if(lr==0){
    #pragma unroll
    for(int j=0;j<4;j++){
      int o = o0 + w*16 + lg*4 + j;
      atomicAdd(&bnacc[o], s1[j]);
      atomicAdd(&bnacc[256+o], s2v[j]);
    }
  }
}

// BN finalize -> scale/shift
__global__ void k_bnfin(const float* __restrict__ bnacc, const float* __restrict__ gamma,
                        const float* __restrict__ beta, float* __restrict__ scsh){
  int o = threadIdx.x;
  float mean = bnacc[o] * (1.f/32768.f);
  float var  = bnacc[256+o] * (1.f/32768.f) - mean*mean;
  float sc = gamma[o] * rsqrtf(var + 1e-5f);
  scsh[o] = sc;
  scsh[256+o] = beta[o] - mean*sc;
}

// out = X + relu(h1*sc + sh); writes one 256-channel half of d_out. 8 elems/thr.
__global__ void k_out(const f16_t* __restrict__ h1, const float* __restrict__ X, long xbstride,
                      const float* __restrict__ scsh, float* __restrict__ out, long ocoff){
  long i = (long)blockIdx.x*256 + threadIdx.x;  // 1,048,576 threads
  long e = i*8;
  int b = (int)(e >> 19);
  int rem = (int)(e & 524287);                  // c*2048 + m
  int c = rem >> 11;
  f16x8 hv = *(const f16x8*)(h1 + e);
  const float* xb = X + (long)b*xbstride + rem;
  float4 xr0 = *(const float4*)xb;
  float4 xr1 = *(const float4*)(xb + 4);
  float sc = scsh[c], sh = scsh[256+c];
  float4 o0, o1;
  o0.x = xr0.x + fmaxf(fmaf((float)hv[0], sc, sh), 0.f);
  o0.y = xr0.y + fmaxf(fmaf((float)hv[1], sc, sh), 0.f);
  o0.z = xr0.z + fmaxf(fmaf((float)hv[2], sc, sh), 0.f);
  o0.w = xr0.w + fmaxf(fmaf((float)hv[3], sc, sh), 0.f);
  o1.x = xr1.x + fmaxf(fmaf((float)hv[4], sc, sh), 0.f);
  o1.y = xr1.y + fmaxf(fmaf((float)hv[5], sc, sh), 0.f);
  o1.z = xr1.z + fmaxf(fmaf((float)hv[6], sc, sh), 0.f);
  o1.w = xr1.w + fmaxf(fmaf((float)hv[7], sc, sh), 0.f);
  float* ob = out + (long)b*(512L*N_) + ocoff + rem;
  *(float4*)ob       = o0;
  *(float4*)(ob + 4) = o1;
}

// ---------------------------------------------------------------------------
extern "C" void kernel_launch(void* const* d_in, const int* in_sizes, int n_in,
                              void* d_out, int out_size, void* d_ws, size_t ws_size,
                              hipStream_t stream){
  (void)in_sizes; (void)n_in; (void)out_size; (void)ws_size;
  const float* x = (const float*)d_in[0];
  const float *Wf[2][4], *bv[2], *bt[2], *gm[2], *bb[2];
  for(int l=0;l<2;l++){
    int base = 1 + l*8;
    Wf[l][0]=(const float*)d_in[base+0];  // Wq
    Wf[l][1]=(const float*)d_in[base+1];  // Wk
    Wf[l][2]=(const float*)d_in[base+2];  // Wv
    bv[l]   =(const float*)d_in[base+3];
    Wf[l][3]=(const float*)d_in[base+4];  // Wt
    bt[l]   =(const float*)d_in[base+5];
    gm[l]   =(const float*)d_in[base+6];
    bb[l]   =(const float*)d_in[base+7];
  }
  char* ws = (char*)d_ws;
  size_t off = 0;
  auto alloc = [&](size_t bytes){ size_t o = off; off += (bytes + 255) & ~(size_t)255; return o; };
  size_t oXt = alloc((size_t)B_*N_*512*2);     // fp16 split x^T
  size_t oXq = alloc((size_t)B_*N_*256*2);     // fp16 split q [n][256]
  size_t oXk = alloc((size_t)B_*N_*256*2);     // fp16 split k [m][256]
  size_t oXv = alloc((size_t)B_*C_*N_*2);      // fp16 v [c][n]
  size_t oH0 = alloc((size_t)B_*N_*C_*2);      // fp16 h0^T [m][c]
  size_t oRo = alloc((size_t)B_*N_*4);         // f32 rowoff
  size_t oBn = alloc(2*512*4);                 // BN accum per layer
  size_t oSc = alloc(2*512*4);                 // BN scale/shift per layer
  size_t oW  = alloc((size_t)786432*2);        // fp16 split weights

  hipMemsetAsync(ws + oBn, 0, 2*512*4, stream);
  k_wconv<<<1536,256,0,stream>>>(Wf[0][0],Wf[0][1],Wf[0][2],Wf[0][3],
                                 Wf[1][0],Wf[1][1],Wf[1][2],Wf[1][3],
                                 (f16_t*)(ws+oW));
  float* dout = (float*)d_out;
  f16_t* H1 = (f16_t*)(ws + oXq);              // aliases Xq (dead when used)
  for(int l=0;l<2;l++){
    const float* Xl = l ? dout : x;
    long xbs = l ? 512L*N_ : 256L*N_;
    const f16_t* WqS = (const f16_t*)(ws+oW) + (size_t)l*393216;
    const f16_t* WkS = WqS + 65536;
    const f16_t* WvS = WqS + 131072;
    const f16_t* WtS = WqS + 262144;
    f16_t* XtS = (f16_t*)(ws+oXt);
    f16_t* Xq  = (f16_t*)(ws+oXq);
    f16_t* Xk  = (f16_t*)(ws+oXk);
    f16_t* Xv  = (f16_t*)(ws+oXv);
    f16_t* H0  = (f16_t*)(ws+oH0);
    float* Ro  = (float*)(ws+oRo);
    float* Bn  = (float*)(ws+oBn) + l*512;
    float* Sc  = (float*)(ws+oSc) + l*512;

    k_transpose<<<dim3(B_, N_/32, C_/64),256,0,stream>>>(Xl, xbs, XtS);
    k_gemm3<1,0><<<dim3(B_,32,2),256,0,stream>>>(XtS, (long)N_*512, WqS, 0L,
                                                 Xq, 256, (long)N_*256, nullptr);
    k_gemm3<1,0><<<dim3(B_,32,2),256,0,stream>>>(XtS, (long)N_*512, WkS, 0L,
                                                 Xk, 256, (long)N_*256, nullptr);
    k_gemm3<0,1><<<dim3(B_,4,32),256,0,stream>>>(WvS, 0L, XtS, (long)N_*512,
                                                 Xv, N_, (long)C_*N_, bv[l]);
    k_rowstats<<<dim3(B_, N_/64),512,0,stream>>>(Xq, Xk, Ro);
    k_apply<<<dim3(B_, 32),256,0,stream>>>(Xq, Xk, Xv, Ro, Xl, xbs, H0);
    k_wt_bn<<<dim3(B_,4,32),256,0,stream>>>(WtS, H0, bt[l], H1, Bn);
    k_bnfin<<<1,256,0,stream>>>(Bn, gm[l], bb[l], Sc);
    k_out<<<4096,256,0,stream>>>(H1, Xl, xbs, Sc, dout, (long)l*C_*N_);
  }
}

// Round 8
// 1886.685 us; speedup vs baseline: 1.0112x; 1.0080x over previous
//
#include <hip/hip_runtime.h>

#define DI __device__ __forceinline__

typedef _Float16 f16_t;
typedef _Float16 f16x8 __attribute__((ext_vector_type(8)));
typedef float    f32x4 __attribute__((ext_vector_type(4)));

static_assert(sizeof(f16x8) == 16, "f16x8 must be 16B");

#define B_  16
#define C_  256
#define CH_ 128
#define N_  2048

DI f32x4 fzero(){ f32x4 z = {0.f,0.f,0.f,0.f}; return z; }
DI f16x8 ldg8(const f16_t* p){ return *(const f16x8*)p; }
DI f32x4 mfma16(f16x8 a, f16x8 b, f32x4 c){
  return __builtin_amdgcn_mfma_f32_16x16x32_f16(a, b, c, 0, 0, 0);
}
DI void split2(float v, f16_t& hi, f16_t& lo){
  hi = (f16_t)v; lo = (f16_t)(v - (float)hi);
}

// ---------------------------------------------------------------------------
// Weight fp32 -> fp16 hi/lo split pack. Per layer: WqS[128][512] WkS[128][512]
// WvS[256][512] WtS[256][512] (cols 0..255 = hi, 256..511 = lo).
__global__ void k_wconv(const float* q1,const float* k1,const float* v1,const float* t1,
                        const float* q2,const float* k2,const float* v2,const float* t2,
                        f16_t* out){
  int i = blockIdx.x*256 + threadIdx.x;            // 0..393215
  int l = (i >= 196608) ? 1 : 0;
  int r = i - l*196608;
  const float* s; long dbase;
  if(r < 32768){ s = l? q2:q1; dbase = 0; }
  else if(r < 65536){ r -= 32768; s = l? k2:k1; dbase = 65536; }
  else if(r < 131072){ r -= 65536; s = l? v2:v1; dbase = 131072; }
  else { r -= 131072; s = l? t2:t1; dbase = 262144; }
  int o = r >> 8, c = r & 255;
  float v = s[o*256 + c];
  f16_t hi, lo; split2(v, hi, lo);
  f16_t* d = out + (long)l*393216 + dbase + (long)o*512;
  d[c] = hi; d[c+256] = lo;
}

// ---------------------------------------------------------------------------
// Transpose+split: XtS[b][n][512] = {hi(x[b][:,n]), lo}. grid (B, N/32, C/64)
__global__ void k_transpose(const float* __restrict__ X, long bstride,
                            f16_t* __restrict__ XtS){
  int b = blockIdx.x, n0 = blockIdx.y*32, c0 = blockIdx.z*64;
  __shared__ float tl[32][65];
  int t = threadIdx.x;
  int nn = t & 31, cr = t >> 5;                     // cr in 0..7
  const float* src = X + (long)b*bstride + n0 + nn;
  #pragma unroll
  for(int i=0;i<8;i++){
    int cc = cr + i*8;
    tl[nn][cc] = src[(long)(c0+cc)*N_];
  }
  __syncthreads();
  int n2 = t >> 3, cq = (t & 7)*8;
  __align__(16) f16_t hi8[8], lo8[8];
  #pragma unroll
  for(int j=0;j<8;j++) split2(tl[n2][cq+j], hi8[j], lo8[j]);
  f16_t* dst = XtS + ((long)b*N_ + n0 + n2)*512 + c0 + cq;
  *(f16x8*)dst         = *(f16x8*)hi8;
  *(f16x8*)(dst + 256) = *(f16x8*)lo8;
}

// ---------------------------------------------------------------------------
// 3-term split GEMM: out[row][col] = sum_k (Ah+Al)[row][k]*(Bh+Bl)[col][k]
// (drops Al*Bl). A,B rows are 512-wide hi|lo, K=256. 64x64 tile, 4 waves.
// b on blockIdx.z (slowest) for XCD/L2 locality.
template<int SPLIT_OUT, int BIAS>
__global__ __launch_bounds__(256) void k_gemm3(
    const f16_t* __restrict__ A, long sA,
    const f16_t* __restrict__ Bt, long sB,
    f16_t* __restrict__ out, int ldo, long sO,
    const float* __restrict__ bias)
{
  int b = blockIdx.z;
  int m0 = blockIdx.x*64, n0 = blockIdx.y*64;
  int t = threadIdx.x, w = t>>6, l = t&63, lr = l&15, lg = l>>4;
  const f16_t* Ab = A + (long)b*sA + (long)(m0 + w*16 + lr)*512;
  const f16_t* Bb = Bt + (long)b*sB;
  f32x4 acc[4];
  #pragma unroll
  for(int i=0;i<4;i++) acc[i] = fzero();
  for(int k=0;k<256;k+=32){
    f16x8 ah = ldg8(Ab + k + lg*8);
    f16x8 al = ldg8(Ab + 256 + k + lg*8);
    #pragma unroll
    for(int ns=0;ns<4;ns++){
      const f16_t* brow = Bb + (long)(n0 + ns*16 + lr)*512;
      f16x8 bh = ldg8(brow + k + lg*8);
      f16x8 bl = ldg8(brow + 256 + k + lg*8);
      acc[ns] = mfma16(ah, bh, acc[ns]);
      acc[ns] = mfma16(ah, bl, acc[ns]);
      acc[ns] = mfma16(al, bh, acc[ns]);
    }
  }
  f16_t* ob = out + (long)b*sO;
  #pragma unroll
  for(int ns=0;ns<4;ns++){
    #pragma unroll
    for(int j=0;j<4;j++){
      int row = m0 + w*16 + lg*4 + j;
      int col = n0 + ns*16 + lr;
      float v = acc[ns][j];
      if(BIAS) v += bias[row];
      if(SPLIT_OUT){
        f16_t hi, lo; split2(v, hi, lo);
        ob[(long)row*ldo + col]       = hi;
        ob[(long)row*ldo + col + 128] = lo;
      } else {
        ob[(long)row*ldo + col] = (f16_t)v;
      }
    }
  }
}

// ---------------------------------------------------------------------------
// Pass 1: rowoff[b][n] = rowmax + ln(sum exp). 8 waves; group g = w>>2 handles
// m in [g*1024,(g+1)*1024); LDS merge at end. grid (N/64, B).
__global__ __launch_bounds__(512,4) void k_rowstats(
    const f16_t* __restrict__ xqS, const f16_t* __restrict__ xkS,
    float* __restrict__ rowoff)
{
  const int n0 = blockIdx.x*64, b = blockIdx.y;
  const int t = threadIdx.x, w = t>>6, l = t&63, lr = l&15, lg = l>>4;
  const int g = w>>2, wg = w&3;
  __shared__ float RS[256];                  // R[2][64] | S[2][64]
  const f16_t* qp = xqS + ((long)b*N_ + n0 + wg*16 + lr)*256;
  f16x8 bqh[4], bql[4];
  #pragma unroll
  for(int k=0;k<4;k++){
    bqh[k] = ldg8(qp + k*32 + lg*8);
    bql[k] = ldg8(qp + 128 + k*32 + lg*8);
  }
  const f16_t* kb = xkS + (long)b*N_*256;
  float rmax = -3e38f, rsum = 0.f;
  for(int m0=g*1024; m0<g*1024+1024; m0+=64){
    #pragma unroll
    for(int s=0;s<4;s++){
      const f16_t* kr = kb + (long)(m0 + s*16 + lr)*256;
      f16x8 ah[4], al_[4];
      #pragma unroll
      for(int k=0;k<4;k++){
        ah[k]  = ldg8(kr + k*32 + lg*8);
        al_[k] = ldg8(kr + 128 + k*32 + lg*8);
      }
      f32x4 a1 = fzero(), a2 = fzero(), a3 = fzero();   // 3 independent chains
      #pragma unroll
      for(int k=0;k<4;k++) a1 = mfma16(ah[k],  bqh[k], a1);
      #pragma unroll
      for(int k=0;k<4;k++) a2 = mfma16(ah[k],  bql[k], a2);
      #pragma unroll
      for(int k=0;k<4;k++) a3 = mfma16(al_[k], bqh[k], a3);
      f32x4 acc = (a1 + a2) + a3;
      float vm = fmaxf(fmaxf(acc[0],acc[1]), fmaxf(acc[2],acc[3]));
      float nm = fmaxf(rmax, vm);
      rsum = rsum*__expf(rmax-nm)
           + __expf(acc[0]-nm)+__expf(acc[1]-nm)+__expf(acc[2]-nm)+__expf(acc[3]-nm);
      rmax = nm;
    }
  }
  #pragma unroll
  for(int off=16; off<64; off<<=1){
    float om = __shfl_xor(rmax, off, 64);
    float os = __shfl_xor(rsum, off, 64);
    float nm = fmaxf(rmax, om);
    rsum = rsum*__expf(rmax-nm) + os*__expf(om-nm);
    rmax = nm;
  }
  if(lg==0){
    RS[g*64 + wg*16 + lr]       = rmax;
    RS[128 + g*64 + wg*16 + lr] = rsum;
  }
  __syncthreads();
  if(g==0 && lg==0){
    int idx = wg*16 + lr;
    float m0v = RS[idx],     m1v = RS[64+idx];
    float s0  = RS[128+idx], s1  = RS[192+idx];
    float mm = fmaxf(m0v, m1v);
    float ss = s0*__expf(m0v-mm) + s1*__expf(m1v-mm);
    rowoff[(long)b*N_ + n0 + idx] = mm + __logf(ss);
  }
}

// ---------------------------------------------------------------------------
// Pass 2 (flash-col, wave-local, full n per block): swapped-operand energy with
// permuted q rows so each lane's 8 P values ARE its PV B-fragment
// (m = w*16+lr, n = lg*8..+7). Online per-column max (defer THR=8). Inline
// two-half h0 epilogue (16KB H) -> LDS 24KB -> 2 blocks/CU. grid (32, B).
__global__ __launch_bounds__(256) void k_apply(
    const f16_t* __restrict__ xqS, const f16_t* __restrict__ xkS,
    const f16_t* __restrict__ xv, const float* __restrict__ rowoff,
    const float* __restrict__ X, long xbstride, f16_t* __restrict__ h0T)
{
  const int mt = blockIdx.x, b = blockIdx.y, m0 = mt*64;
  const int t = threadIdx.x, w = t>>6, l = t&63, lr = l&15, lg = l>>4;
  __shared__ __align__(16) char smem[24576];
  f16_t* H    = (f16_t*)smem;                  // 16KB [64 m][128 c] swizzled (epilogue)
  float* ro_s = (float*)(smem + 16384);        // 8KB rowoff cache (loop)
  {
    const float* rob = rowoff + (long)b*N_;
    *(f32x4*)(ro_s + t*4)        = *(const f32x4*)(rob + t*4);
    *(f32x4*)(ro_s + t*4 + 1024) = *(const f32x4*)(rob + t*4 + 1024);
  }
  __syncthreads();

  const f16_t* akp = xkS + ((long)b*N_ + m0 + w*16 + lr)*256;
  f16x8 akh[4], akl[4];
  #pragma unroll
  for(int k=0;k<4;k++){
    akh[k] = ldg8(akp + k*32 + lg*8);
    akl[k] = ldg8(akp + 128 + k*32 + lg*8);
  }

  const f16_t* xqb = xqS + (long)b*N_*256;
  const f16_t* xvb = xv + (long)b*C_*N_ + (long)lr*N_;   // + cf*16 rows
  const int qperm = ((lr>>2)*8 + (lr&3));                // + s2*4

  f32x4 y[16];
  #pragma unroll
  for(int i=0;i<16;i++) y[i] = fzero();
  float cs = 0.f, cm = -3e38f;

  #pragma unroll 1
  for(int n0=0; n0<N_; n0+=32){
    // ---- energies -> g[s2][j] = e[n = n0+lg*8+s2*4+j][m = m0+w*16+lr] - ro[n]
    float g[2][4];
    #pragma unroll
    for(int s2=0;s2<2;s2++){
      const f16_t* qr = xqb + (long)(n0 + qperm + s2*4)*256;
      f16x8 qh[4], ql[4];
      #pragma unroll
      for(int k=0;k<4;k++){
        qh[k] = ldg8(qr + k*32 + lg*8);
        ql[k] = ldg8(qr + 128 + k*32 + lg*8);
      }
      f32x4 e1 = fzero(), e2 = fzero(), e3 = fzero();
      #pragma unroll
      for(int k=0;k<4;k++) e1 = mfma16(qh[k], akh[k], e1);
      #pragma unroll
      for(int k=0;k<4;k++) e2 = mfma16(ql[k], akh[k], e2);
      #pragma unroll
      for(int k=0;k<4;k++) e3 = mfma16(qh[k], akl[k], e3);
      f32x4 e = (e1 + e2) + e3;
      f32x4 ro4 = *(const f32x4*)(ro_s + n0 + lg*8 + s2*4);
      #pragma unroll
      for(int j=0;j<4;j++) g[s2][j] = e[j] - ro4[j];
    }
    // ---- per-column (m=lr) chunk max: in-lane 8, then 2 shfl across lg ----
    float v = fmaxf(fmaxf(fmaxf(g[0][0],g[0][1]), fmaxf(g[0][2],g[0][3])),
                    fmaxf(fmaxf(g[1][0],g[1][1]), fmaxf(g[1][2],g[1][3])));
    v = fmaxf(v, __shfl_xor(v, 16, 64));
    v = fmaxf(v, __shfl_xor(v, 32, 64));
    bool need = v > cm + 8.f;
    float fj = need ? __expf(cm - v) : 1.f;
    if(need) cm = v;
    cs *= fj;
    // ---- P (fp16) in-register = PV B-frag; colsum from SAME rounded values
    __align__(16) f16_t pv[8];
    #pragma unroll
    for(int s2=0;s2<2;s2++){
      #pragma unroll
      for(int j=0;j<4;j++){
        float p = __expf(g[s2][j] - cm);
        f16_t pb = (f16_t)p;
        cs += (float)pb;
        pv[s2*4+j] = pb;
      }
    }
    f16x8 pfrag = *(const f16x8*)pv;
    if(__any(need)){
      #pragma unroll
      for(int cf=0;cf<16;cf++){
        #pragma unroll
        for(int j2=0;j2<4;j2++) y[cf][j2] *= fj;
      }
    }
    // ---- PV: y[cf] covers c = cf*16 + lg*4 + j, m = lr (col) ----
    #pragma unroll
    for(int cf=0;cf<16;cf++){
      f16x8 av = ldg8(xvb + (long)cf*16*N_ + n0 + lg*8);
      y[cf] = mfma16(av, pfrag, y[cf]);
    }
  }

  // colsum across the 4 lg lane-groups (butterfly -> all lanes)
  cs += __shfl_xor(cs, 16, 64);
  cs += __shfl_xor(cs, 32, 64);
  float inv = 1.f/(1e-9f*__expf(-cm) + cs);

  // ---- two-half epilogue: x_r -> H (16KB), h0 = X - x_r -> h0T ----
  const int mq = t&63, cq = t>>6;
  const float* Xb = X + (long)b*xbstride + m0;
  uint4* dstb = (uint4*)(h0T + ((long)b*N_ + m0)*C_);
  #pragma unroll
  for(int half=0; half<2; half++){
    #pragma unroll
    for(int cf8=0; cf8<8; cf8++){
      int cf = half*8 + cf8;
      #pragma unroll
      for(int j=0;j<4;j++){
        int cl = cf8*16 + lg*4 + j;                 // 0..127
        int m  = w*16 + lr;
        *(f16_t*)((char*)H + m*256 + ((((cl>>3) ^ (m&7))<<4) | ((cl&7)<<1)))
          = (f16_t)(y[cf][j]*inv);
      }
    }
    __syncthreads();
    #pragma unroll 4
    for(int ci=0; ci<32; ci++){
      int cl = cq*32 + ci;
      int c  = half*128 + cl;
      f16_t* hp = (f16_t*)((char*)H + mq*256 + ((((cl>>3) ^ (mq&7))<<4) | ((cl&7)<<1)));
      *hp = (f16_t)(Xb[(long)c*N_ + mq] - (float)*hp);
    }
    __syncthreads();
    {
      const uint4* src = (const uint4*)H;
      for(int i=t;i<1024;i+=256){
        int row = i>>4, slot = i&15;
        dstb[row*32 + half*16 + slot] = src[(i & ~15) | (slot ^ (row&7))];
      }
    }
    __syncthreads();
  }
}

// ---------------------------------------------------------------------------
// h1[b][o][m] = Wt @ h0 + bt (2-term: Wt hi+lo), fp16 out + BN partial sums.
// grid (4, 32, B).
__global__ __launch_bounds__(256) void k_wt_bn(
    const f16_t* __restrict__ WtS, const f16_t* __restrict__ h0T,
    const float* __restrict__ bt,
    f16_t* __restrict__ h1, float* __restrict__ bnacc)
{
  int o0 = blockIdx.x*64, m0 = blockIdx.y*64, b = blockIdx.z;
  int t=threadIdx.x, w=t>>6, l=t&63, lr=l&15, lg=l>>4;
  const f16_t* Arow = WtS + (long)(o0 + w*16 + lr)*512;
  const f16_t* Bb = h0T + (long)b*N_*C_;
  f32x4 acc[4];
  #pragma unroll
  for(int i=0;i<4;i++) acc[i] = fzero();
  for(int k=0;k<C_;k+=32){
    f16x8 afh = ldg8(Arow + k + lg*8);
    f16x8 afl = ldg8(Arow + 256 + k + lg*8);
    #pragma unroll
    for(int ms=0;ms<4;ms++){
      f16x8 bf_ = ldg8(Bb + (long)(m0 + ms*16 + lr)*C_ + k + lg*8);
      acc[ms] = mfma16(afh, bf_, acc[ms]);
      acc[ms] = mfma16(afl, bf_, acc[ms]);
    }
  }
  float s1[4]={0.f,0.f,0.f,0.f}, s2v[4]={0.f,0.f,0.f,0.f};
  f16_t* h1b = h1 + (long)b*C_*N_;
  #pragma unroll
  for(int j=0;j<4;j++){
    int o = o0 + w*16 + lg*4 + j;
    float bias = bt[o];
    #pragma unroll
    for(int ms=0;ms<4;ms++){
      float v = acc[ms][j] + bias;
      h1b[(long)o*N_ + m0 + ms*16 + lr] = (f16_t)v;
      s1[j] += v; s2v[j] += v*v;
    }
  }
  #pragma unroll
  for(int off=1; off<16; off<<=1){
    #pragma unroll
    for(int j=0;j<4;j++){ s1[j]+=__shfl_xor(s1[j],off,64); s2v[j]+=__shfl_xor(s2v[j],off,64); }
  }
  if(lr==0){
    #pragma unroll
    for(int j=0;j<4;j++){
      int o = o0 + w*16 + lg*4 + j;
      atomicAdd(&bnacc[o], s1[j]);
      atomicAdd(&bnacc[256+o], s2v[j]);
    }
  }
}

// BN finalize -> scale/shift
__global__ void k_bnfin(const float* __restrict__ bnacc, const float* __restrict__ gamma,
                        const float* __restrict__ beta, float* __restrict__ scsh){
  int o = threadIdx.x;
  float mean = bnacc[o] * (1.f/32768.f);
  float var  = bnacc[256+o] * (1.f/32768.f) - mean*mean;
  float sc = gamma[o] * rsqrtf(var + 1e-5f);
  scsh[o] = sc;
  scsh[256+o] = beta[o] - mean*sc;
}

// out = X + relu(h1*sc + sh); writes one 256-channel half of d_out. 8 elems/thr.
__global__ void k_out(const f16_t* __restrict__ h1, const float* __restrict__ X, long xbstride,
                      const float* __restrict__ scsh, float* __restrict__ out, long ocoff){
  long i = (long)blockIdx.x*256 + threadIdx.x;  // 1,048,576 threads
  long e = i*8;
  int b = (int)(e >> 19);
  int rem = (int)(e & 524287);                  // c*2048 + m
  int c = rem >> 11;
  f16x8 hv = *(const f16x8*)(h1 + e);
  const float* xb = X + (long)b*xbstride + rem;
  float4 xr0 = *(const float4*)xb;
  float4 xr1 = *(const float4*)(xb + 4);
  float sc = scsh[c], sh = scsh[256+c];
  float4 o0, o1;
  o0.x = xr0.x + fmaxf(fmaf((float)hv[0], sc, sh), 0.f);
  o0.y = xr0.y + fmaxf(fmaf((float)hv[1], sc, sh), 0.f);
  o0.z = xr0.z + fmaxf(fmaf((float)hv[2], sc, sh), 0.f);
  o0.w = xr0.w + fmaxf(fmaf((float)hv[3], sc, sh), 0.f);
  o1.x = xr1.x + fmaxf(fmaf((float)hv[4], sc, sh), 0.f);
  o1.y = xr1.y + fmaxf(fmaf((float)hv[5], sc, sh), 0.f);
  o1.z = xr1.z + fmaxf(fmaf((float)hv[6], sc, sh), 0.f);
  o1.w = xr1.w + fmaxf(fmaf((float)hv[7], sc, sh), 0.f);
  float* ob = out + (long)b*(512L*N_) + ocoff + rem;
  *(float4*)ob       = o0;
  *(float4*)(ob + 4) = o1;
}

// ---------------------------------------------------------------------------
extern "C" void kernel_launch(void* const* d_in, const int* in_sizes, int n_in,
                              void* d_out, int out_size, void* d_ws, size_t ws_size,
                              hipStream_t stream){
  (void)in_sizes; (void)n_in; (void)out_size; (void)ws_size;
  const float* x = (const float*)d_in[0];
  const float *Wf[2][4], *bv[2], *bt[2], *gm[2], *bb[2];
  for(int l=0;l<2;l++){
    int base = 1 + l*8;
    Wf[l][0]=(const float*)d_in[base+0];  // Wq
    Wf[l][1]=(const float*)d_in[base+1];  // Wk
    Wf[l][2]=(const float*)d_in[base+2];  // Wv
    bv[l]   =(const float*)d_in[base+3];
    Wf[l][3]=(const float*)d_in[base+4];  // Wt
    bt[l]   =(const float*)d_in[base+5];
    gm[l]   =(const float*)d_in[base+6];
    bb[l]   =(const float*)d_in[base+7];
  }
  char* ws = (char*)d_ws;
  size_t off = 0;
  auto alloc = [&](size_t bytes){ size_t o = off; off += (bytes + 255) & ~(size_t)255; return o; };
  size_t oXt = alloc((size_t)B_*N_*512*2);     // fp16 split x^T
  size_t oXq = alloc((size_t)B_*N_*256*2);     // fp16 split q [n][256]
  size_t oXk = alloc((size_t)B_*N_*256*2);     // fp16 split k [m][256]
  size_t oXv = alloc((size_t)B_*C_*N_*2);      // fp16 v [c][n]
  size_t oH0 = alloc((size_t)B_*N_*C_*2);      // fp16 h0^T [m][c]
  size_t oRo = alloc((size_t)B_*N_*4);         // f32 rowoff
  size_t oBn = alloc(2*512*4);                 // BN accum per layer
  size_t oSc = alloc(2*512*4);                 // BN scale/shift per layer
  size_t oW  = alloc((size_t)786432*2);        // fp16 split weights

  hipMemsetAsync(ws + oBn, 0, 2*512*4, stream);
  k_wconv<<<1536,256,0,stream>>>(Wf[0][0],Wf[0][1],Wf[0][2],Wf[0][3],
                                 Wf[1][0],Wf[1][1],Wf[1][2],Wf[1][3],
                                 (f16_t*)(ws+oW));
  float* dout = (float*)d_out;
  f16_t* H1 = (f16_t*)(ws + oXq);              // aliases Xq (dead when used)
  for(int l=0;l<2;l++){
    const float* Xl = l ? dout : x;
    long xbs = l ? 512L*N_ : 256L*N_;
    const f16_t* WqS = (const f16_t*)(ws+oW) + (size_t)l*393216;
    const f16_t* WkS = WqS + 65536;
    const f16_t* WvS = WqS + 131072;
    const f16_t* WtS = WqS + 262144;
    f16_t* XtS = (f16_t*)(ws+oXt);
    f16_t* Xq  = (f16_t*)(ws+oXq);
    f16_t* Xk  = (f16_t*)(ws+oXk);
    f16_t* Xv  = (f16_t*)(ws+oXv);
    f16_t* H0  = (f16_t*)(ws+oH0);
    float* Ro  = (float*)(ws+oRo);
    float* Bn  = (float*)(ws+oBn) + l*512;
    float* Sc  = (float*)(ws+oSc) + l*512;

    k_transpose<<<dim3(B_, N_/32, C_/64),256,0,stream>>>(Xl, xbs, XtS);
    k_gemm3<1,0><<<dim3(32,2,B_),256,0,stream>>>(XtS, (long)N_*512, WqS, 0L,
                                                 Xq, 256, (long)N_*256, nullptr);
    k_gemm3<1,0><<<dim3(32,2,B_),256,0,stream>>>(XtS, (long)N_*512, WkS, 0L,
                                                 Xk, 256, (long)N_*256, nullptr);
    k_gemm3<0,1><<<dim3(4,32,B_),256,0,stream>>>(WvS, 0L, XtS, (long)N_*512,
                                                 Xv, N_, (long)C_*N_, bv[l]);
    k_rowstats<<<dim3(N_/64, B_),512,0,stream>>>(Xq, Xk, Ro);
    k_apply<<<dim3(32, B_),256,0,stream>>>(Xq, Xk, Xv, Ro, Xl, xbs, H0);
    k_wt_bn<<<dim3(4,32,B_),256,0,stream>>>(WtS, H0, bt[l], H1, Bn);
    k_bnfin<<<1,256,0,stream>>>(Bn, gm[l], bb[l], Sc);
    k_out<<<4096,256,0,stream>>>(H1, Xl, xbs, Sc, dout, (long)l*C_*N_);
  }
}

// Round 9
// 1560.436 us; speedup vs baseline: 1.2226x; 1.2091x over previous
//
#include <hip/hip_runtime.h>

#define DI __device__ __forceinline__

typedef _Float16 f16_t;
typedef _Float16 f16x8 __attribute__((ext_vector_type(8)));
typedef float    f32x4 __attribute__((ext_vector_type(4)));

static_assert(sizeof(f16x8) == 16, "f16x8 must be 16B");

#define B_  16
#define C_  256
#define CH_ 128
#define N_  2048

DI f32x4 fzero(){ f32x4 z = {0.f,0.f,0.f,0.f}; return z; }
DI f16x8 ldg8(const f16_t* p){ return *(const f16x8*)p; }
DI f32x4 mfma16(f16x8 a, f16x8 b, f32x4 c){
  return __builtin_amdgcn_mfma_f32_16x16x32_f16(a, b, c, 0, 0, 0);
}
DI void split2(float v, f16_t& hi, f16_t& lo){
  hi = (f16_t)v; lo = (f16_t)(v - (float)hi);
}
// XCD-pair swizzle: blocks i≡x (mod 8) land on XCD x; give XCD x batches {2x,2x+1}
DI int swz_b(int i){ return ((i&7)<<1) | ((i>>3)&1); }

// ---------------------------------------------------------------------------
// Weight fp32 -> fp16 hi/lo split pack. Per layer: WqS[128][512] WkS[128][512]
// WvS[256][512] WtS[256][512] (cols 0..255 = hi, 256..511 = lo).
__global__ void k_wconv(const float* q1,const float* k1,const float* v1,const float* t1,
                        const float* q2,const float* k2,const float* v2,const float* t2,
                        f16_t* out){
  int i = blockIdx.x*256 + threadIdx.x;            // 0..393215
  int l = (i >= 196608) ? 1 : 0;
  int r = i - l*196608;
  const float* s; long dbase;
  if(r < 32768){ s = l? q2:q1; dbase = 0; }
  else if(r < 65536){ r -= 32768; s = l? k2:k1; dbase = 65536; }
  else if(r < 131072){ r -= 65536; s = l? v2:v1; dbase = 131072; }
  else { r -= 131072; s = l? t2:t1; dbase = 262144; }
  int o = r >> 8, c = r & 255;
  float v = s[o*256 + c];
  f16_t hi, lo; split2(v, hi, lo);
  f16_t* d = out + (long)l*393216 + dbase + (long)o*512;
  d[c] = hi; d[c+256] = lo;
}

// ---------------------------------------------------------------------------
// Transpose+split: XtS[b][n][512] = {hi(x[b][:,n]), lo}. grid (B, N/32, C/64)
__global__ void k_transpose(const float* __restrict__ X, long bstride,
                            f16_t* __restrict__ XtS){
  int b = blockIdx.x, n0 = blockIdx.y*32, c0 = blockIdx.z*64;
  __shared__ float tl[32][65];
  int t = threadIdx.x;
  int nn = t & 31, cr = t >> 5;                     // cr in 0..7
  const float* src = X + (long)b*bstride + n0 + nn;
  #pragma unroll
  for(int i=0;i<8;i++){
    int cc = cr + i*8;
    tl[nn][cc] = src[(long)(c0+cc)*N_];
  }
  __syncthreads();
  int n2 = t >> 3, cq = (t & 7)*8;
  __align__(16) f16_t hi8[8], lo8[8];
  #pragma unroll
  for(int j=0;j<8;j++) split2(tl[n2][cq+j], hi8[j], lo8[j]);
  f16_t* dst = XtS + ((long)b*N_ + n0 + n2)*512 + c0 + cq;
  *(f16x8*)dst         = *(f16x8*)hi8;
  *(f16x8*)(dst + 256) = *(f16x8*)lo8;
}

// ---------------------------------------------------------------------------
// 3-term split GEMM: out[row][col] = sum_k (Ah+Al)[row][k]*(Bh+Bl)[col][k]
// (drops Al*Bl). A,B rows are 512-wide hi|lo, K=256. 64x64 tile, 4 waves.
// 1-D grid, XCD-pair swizzle; m-tile = (r & (2^LGX-1)), n-tile = r >> LGX.
template<int LGX, int SPLIT_OUT, int BIAS>
__global__ __launch_bounds__(256) void k_gemm3(
    const f16_t* __restrict__ A, long sA,
    const f16_t* __restrict__ Bt, long sB,
    f16_t* __restrict__ out, int ldo, long sO,
    const float* __restrict__ bias)
{
  int i = blockIdx.x;
  int b = swz_b(i);
  int r = i>>4;
  int m0 = (r & ((1<<LGX)-1))*64, n0 = (r >> LGX)*64;
  int t = threadIdx.x, w = t>>6, l = t&63, lr = l&15, lg = l>>4;
  const f16_t* Ab = A + (long)b*sA + (long)(m0 + w*16 + lr)*512;
  const f16_t* Bb = Bt + (long)b*sB;
  f32x4 acc[4];
  #pragma unroll
  for(int i2=0;i2<4;i2++) acc[i2] = fzero();
  for(int k=0;k<256;k+=32){
    f16x8 ah = ldg8(Ab + k + lg*8);
    f16x8 al = ldg8(Ab + 256 + k + lg*8);
    #pragma unroll
    for(int ns=0;ns<4;ns++){
      const f16_t* brow = Bb + (long)(n0 + ns*16 + lr)*512;
      f16x8 bh = ldg8(brow + k + lg*8);
      f16x8 bl = ldg8(brow + 256 + k + lg*8);
      acc[ns] = mfma16(ah, bh, acc[ns]);
      acc[ns] = mfma16(ah, bl, acc[ns]);
      acc[ns] = mfma16(al, bh, acc[ns]);
    }
  }
  f16_t* ob = out + (long)b*sO;
  #pragma unroll
  for(int ns=0;ns<4;ns++){
    #pragma unroll
    for(int j=0;j<4;j++){
      int row = m0 + w*16 + lg*4 + j;
      int col = n0 + ns*16 + lr;
      float v = acc[ns][j];
      if(BIAS) v += bias[row];
      if(SPLIT_OUT){
        f16_t hi, lo; split2(v, hi, lo);
        ob[(long)row*ldo + col]       = hi;
        ob[(long)row*ldo + col + 128] = lo;
      } else {
        ob[(long)row*ldo + col] = (f16_t)v;
      }
    }
  }
}

// ---------------------------------------------------------------------------
// Pass 1: rowoff[b][n] = rowmax + ln(sum exp). 8 waves; group g = w>>2 handles
// m in [g*1024,(g+1)*1024); LDS merge at end. 1-D grid 512, XCD swizzle.
__global__ __launch_bounds__(512,4) void k_rowstats(
    const f16_t* __restrict__ xqS, const f16_t* __restrict__ xkS,
    float* __restrict__ rowoff)
{
  const int i = blockIdx.x;
  const int b = swz_b(i);
  const int n0 = (i>>4)*64;
  const int t = threadIdx.x, w = t>>6, l = t&63, lr = l&15, lg = l>>4;
  const int g = w>>2, wg = w&3;
  __shared__ float RS[256];                  // R[2][64] | S[2][64]
  const f16_t* qp = xqS + ((long)b*N_ + n0 + wg*16 + lr)*256;
  f16x8 bqh[4], bql[4];
  #pragma unroll
  for(int k=0;k<4;k++){
    bqh[k] = ldg8(qp + k*32 + lg*8);
    bql[k] = ldg8(qp + 128 + k*32 + lg*8);
  }
  const f16_t* kb = xkS + (long)b*N_*256;
  float rmax = -3e38f, rsum = 0.f;
  for(int m0=g*1024; m0<g*1024+1024; m0+=64){
    #pragma unroll
    for(int s=0;s<4;s++){
      const f16_t* kr = kb + (long)(m0 + s*16 + lr)*256;
      f16x8 ah[4], al_[4];
      #pragma unroll
      for(int k=0;k<4;k++){
        ah[k]  = ldg8(kr + k*32 + lg*8);
        al_[k] = ldg8(kr + 128 + k*32 + lg*8);
      }
      f32x4 a1 = fzero(), a2 = fzero(), a3 = fzero();   // 3 independent chains
      #pragma unroll
      for(int k=0;k<4;k++) a1 = mfma16(ah[k],  bqh[k], a1);
      #pragma unroll
      for(int k=0;k<4;k++) a2 = mfma16(ah[k],  bql[k], a2);
      #pragma unroll
      for(int k=0;k<4;k++) a3 = mfma16(al_[k], bqh[k], a3);
      f32x4 acc = (a1 + a2) + a3;
      float vm = fmaxf(fmaxf(acc[0],acc[1]), fmaxf(acc[2],acc[3]));
      float nm = fmaxf(rmax, vm);
      rsum = rsum*__expf(rmax-nm)
           + __expf(acc[0]-nm)+__expf(acc[1]-nm)+__expf(acc[2]-nm)+__expf(acc[3]-nm);
      rmax = nm;
    }
  }
  #pragma unroll
  for(int off=16; off<64; off<<=1){
    float om = __shfl_xor(rmax, off, 64);
    float os = __shfl_xor(rsum, off, 64);
    float nm = fmaxf(rmax, om);
    rsum = rsum*__expf(rmax-nm) + os*__expf(om-nm);
    rmax = nm;
  }
  if(lg==0){
    RS[g*64 + wg*16 + lr]       = rmax;
    RS[128 + g*64 + wg*16 + lr] = rsum;
  }
  __syncthreads();
  if(g==0 && lg==0){
    int idx = wg*16 + lr;
    float m0v = RS[idx],     m1v = RS[64+idx];
    float s0  = RS[128+idx], s1  = RS[192+idx];
    float mm = fmaxf(m0v, m1v);
    float ss = s0*__expf(m0v-mm) + s1*__expf(m1v-mm);
    rowoff[(long)b*N_ + n0 + idx] = mm + __logf(ss);
  }
}

// ---------------------------------------------------------------------------
// Pass 2 (flash-col, wave-local): V tile staged in LDS once per block-chunk
// (thread t = channel row t, 80B row stride -> conflict-free b128 reads);
// all q loads hoisted to chunk top -> ONE latency window per chunk.
// Swapped-operand energy, lane's 8 P values = PV B-frag. Defer-max THR=8.
// Inline two-half h0 epilogue. 1-D grid 512, XCD swizzle.
__global__ __launch_bounds__(256) void k_apply(
    const f16_t* __restrict__ xqS, const f16_t* __restrict__ xkS,
    const f16_t* __restrict__ xv, const float* __restrict__ rowoff,
    const float* __restrict__ X, long xbstride, f16_t* __restrict__ h0T)
{
  const int i = blockIdx.x;
  const int b = swz_b(i);
  const int m0 = (i>>4)*64;
  const int t = threadIdx.x, w = t>>6, l = t&63, lr = l&15, lg = l>>4;
  __shared__ __align__(16) char smem[28672];
  f16_t* Vs   = (f16_t*)smem;                  // [256 c][80B] = 20480 (loop)
  f16_t* H    = (f16_t*)smem;                  // 16KB epilogue (aliases Vs)
  float* ro_s = (float*)(smem + 20480);        // 8KB rowoff cache
  {
    const float* rob = rowoff + (long)b*N_;
    *(f32x4*)(ro_s + t*4)        = *(const f32x4*)(rob + t*4);
    *(f32x4*)(ro_s + t*4 + 1024) = *(const f32x4*)(rob + t*4 + 1024);
  }

  const f16_t* akp = xkS + ((long)b*N_ + m0 + w*16 + lr)*256;
  f16x8 akh[4], akl[4];
  #pragma unroll
  for(int k=0;k<4;k++){
    akh[k] = ldg8(akp + k*32 + lg*8);
    akl[k] = ldg8(akp + 128 + k*32 + lg*8);
  }

  const f16_t* xqb  = xqS + (long)b*N_*256;
  const f16_t* vsrc = xv + (long)b*C_*N_ + (long)t*N_;   // staging row = channel t
  const int qperm = ((lr>>2)*8 + (lr&3));                // + s2*4

  f32x4 y[16];
  #pragma unroll
  for(int i2=0;i2<16;i2++) y[i2] = fzero();
  float cs = 0.f, cm = -3e38f;
  __syncthreads();                                       // ro_s ready

  #pragma unroll 1
  for(int n0=0; n0<N_; n0+=32){
    // ---- issue ALL global loads for this chunk up front ----
    f16x8 vr0 = ldg8(vsrc + n0);
    f16x8 vr1 = ldg8(vsrc + n0 + 8);
    f16x8 vr2 = ldg8(vsrc + n0 + 16);
    f16x8 vr3 = ldg8(vsrc + n0 + 24);
    f16x8 qh[2][4], ql[2][4];
    #pragma unroll
    for(int s2=0;s2<2;s2++){
      const f16_t* qr = xqb + (long)(n0 + qperm + s2*4)*256;
      #pragma unroll
      for(int k=0;k<4;k++){
        qh[s2][k] = ldg8(qr + k*32 + lg*8);
        ql[s2][k] = ldg8(qr + 128 + k*32 + lg*8);
      }
    }
    // ---- V -> LDS ----
    {
      char* vrow = (char*)Vs + t*80;
      *(f16x8*)(vrow)      = vr0;
      *(f16x8*)(vrow + 16) = vr1;
      *(f16x8*)(vrow + 32) = vr2;
      *(f16x8*)(vrow + 48) = vr3;
    }
    __syncthreads();
    // ---- energies -> g[s2][j] = e[n = n0+lg*8+s2*4+j][m = m0+w*16+lr] - ro[n]
    float g[2][4];
    #pragma unroll
    for(int s2=0;s2<2;s2++){
      f32x4 e1 = fzero(), e2 = fzero(), e3 = fzero();
      #pragma unroll
      for(int k=0;k<4;k++) e1 = mfma16(qh[s2][k], akh[k], e1);
      #pragma unroll
      for(int k=0;k<4;k++) e2 = mfma16(ql[s2][k], akh[k], e2);
      #pragma unroll
      for(int k=0;k<4;k++) e3 = mfma16(qh[s2][k], akl[k], e3);
      f32x4 e = (e1 + e2) + e3;
      f32x4 ro4 = *(const f32x4*)(ro_s + n0 + lg*8 + s2*4);
      #pragma unroll
      for(int j=0;j<4;j++) g[s2][j] = e[j] - ro4[j];
    }
    // ---- per-column (m=lr) chunk max: in-lane 8, then 2 shfl across lg ----
    float v = fmaxf(fmaxf(fmaxf(g[0][0],g[0][1]), fmaxf(g[0][2],g[0][3])),
                    fmaxf(fmaxf(g[1][0],g[1][1]), fmaxf(g[1][2],g[1][3])));
    v = fmaxf(v, __shfl_xor(v, 16, 64));
    v = fmaxf(v, __shfl_xor(v, 32, 64));
    bool need = v > cm + 8.f;
    float fj = need ? __expf(cm - v) : 1.f;
    if(need) cm = v;
    cs *= fj;
    // ---- P (fp16) in-register = PV B-frag; colsum from SAME rounded values
    __align__(16) f16_t pv[8];
    #pragma unroll
    for(int s2=0;s2<2;s2++){
      #pragma unroll
      for(int j=0;j<4;j++){
        float p = __expf(g[s2][j] - cm);
        f16_t pb = (f16_t)p;
        cs += (float)pb;
        pv[s2*4+j] = pb;
      }
    }
    f16x8 pfrag = *(const f16x8*)pv;
    if(__any(need)){
      #pragma unroll
      for(int cf=0;cf<16;cf++){
        #pragma unroll
        for(int j2=0;j2<4;j2++) y[cf][j2] *= fj;
      }
    }
    // ---- PV from LDS: y[cf] covers c = cf*16 + lg*4 + j, m = lr (col) ----
    #pragma unroll
    for(int cf=0;cf<16;cf++){
      f16x8 av = *(const f16x8*)((const char*)Vs + (cf*16 + lr)*80 + lg*16);
      y[cf] = mfma16(av, pfrag, y[cf]);
    }
    __syncthreads();
  }

  // colsum across the 4 lg lane-groups (butterfly -> all lanes)
  cs += __shfl_xor(cs, 16, 64);
  cs += __shfl_xor(cs, 32, 64);
  float inv = 1.f/(1e-9f*__expf(-cm) + cs);

  // ---- two-half epilogue: x_r -> H (16KB), h0 = X - x_r -> h0T ----
  const int mq = t&63, cq = t>>6;
  const float* Xb = X + (long)b*xbstride + m0;
  uint4* dstb = (uint4*)(h0T + ((long)b*N_ + m0)*C_);
  #pragma unroll
  for(int half=0; half<2; half++){
    #pragma unroll
    for(int cf8=0; cf8<8; cf8++){
      int cf = half*8 + cf8;
      #pragma unroll
      for(int j=0;j<4;j++){
        int cl = cf8*16 + lg*4 + j;                 // 0..127
        int m  = w*16 + lr;
        *(f16_t*)((char*)H + m*256 + ((((cl>>3) ^ (m&7))<<4) | ((cl&7)<<1)))
          = (f16_t)(y[cf][j]*inv);
      }
    }
    __syncthreads();
    #pragma unroll 4
    for(int ci=0; ci<32; ci++){
      int cl = cq*32 + ci;
      int c  = half*128 + cl;
      f16_t* hp = (f16_t*)((char*)H + mq*256 + ((((cl>>3) ^ (mq&7))<<4) | ((cl&7)<<1)));
      *hp = (f16_t)(Xb[(long)c*N_ + mq] - (float)*hp);
    }
    __syncthreads();
    {
      const uint4* src = (const uint4*)H;
      for(int i2=t;i2<1024;i2+=256){
        int row = i2>>4, slot = i2&15;
        dstb[row*32 + half*16 + slot] = src[(i2 & ~15) | (slot ^ (row&7))];
      }
    }
    __syncthreads();
  }
}

// ---------------------------------------------------------------------------
// h1[b][o][m] = Wt @ h0 + bt (2-term: Wt hi+lo), fp16 out + BN partial sums.
// 1-D grid 2048, XCD swizzle.
__global__ __launch_bounds__(256) void k_wt_bn(
    const f16_t* __restrict__ WtS, const f16_t* __restrict__ h0T,
    const float* __restrict__ bt,
    f16_t* __restrict__ h1, float* __restrict__ bnacc)
{
  int i = blockIdx.x;
  int b = swz_b(i);
  int r = i>>4;
  int o0 = (r&3)*64, m0 = (r>>2)*64;
  int t=threadIdx.x, w=t>>6, l=t&63, lr=l&15, lg=l>>4;
  const f16_t* Arow = WtS + (long)(o0 + w*16 + lr)*512;
  const f16_t* Bb = h0T + (long)b*N_*C_;
  f32x4 acc[4];
  #pragma unroll
  for(int i2=0;i2<4;i2++) acc[i2] = fzero();
  for(int k=0;k<C_;k+=32){
    f16x8 afh = ldg8(Arow + k + lg*8);
    f16x8 afl = ldg8(Arow + 256 + k + lg*8);
    #pragma unroll
    for(int ms=0;ms<4;ms++){
      f16x8 bf_ = ldg8(Bb + (long)(m0 + ms*16 + lr)*C_ + k + lg*8);
      acc[ms] = mfma16(afh, bf_, acc[ms]);
      acc[ms] = mfma16(afl, bf_, acc[ms]);
    }
  }
  float s1[4]={0.f,0.f,0.f,0.f}, s2v[4]={0.f,0.f,0.f,0.f};
  f16_t* h1b = h1 + (long)b*C_*N_;
  #pragma unroll
  for(int j=0;j<4;j++){
    int o = o0 + w*16 + lg*4 + j;
    float bias = bt[o];
    #pragma unroll
    for(int ms=0;ms<4;ms++){
      float v = acc[ms][j] + bias;
      h1b[(long)o*N_ + m0 + ms*16 + lr] = (f16_t)v;
      s1[j] += v; s2v[j] += v*v;
    }
  }
  #pragma unroll
  for(int off=1; off<16; off<<=1){
    #pragma unroll
    for(int j=0;j<4;j++){ s1[j]+=__shfl_xor(s1[j],off,64); s2v[j]+=__shfl_xor(s2v[j],off,64); }
  }
  if(lr==0){
    #pragma unroll
    for(int j=0;j<4;j++){
      int o = o0 + w*16 + lg*4 + j;
      atomicAdd(&bnacc[o], s1[j]);
      atomicAdd(&bnacc[256+o], s2v[j]);
    }
  }
}

// BN finalize -> scale/shift
__global__ void k_bnfin(const float* __restrict__ bnacc, const float* __restrict__ gamma,
                        const float* __restrict__ beta, float* __restrict__ scsh){
  int o = threadIdx.x;
  float mean = bnacc[o] * (1.f/32768.f);
  float var  = bnacc[256+o] * (1.f/32768.f) - mean*mean;
  float sc = gamma[o] * rsqrtf(var + 1e-5f);
  scsh[o] = sc;
  scsh[256+o] = beta[o] - mean*sc;
}

// out = X + relu(h1*sc + sh); writes one 256-channel half of d_out. 8 elems/thr.
__global__ void k_out(const f16_t* __restrict__ h1, const float* __restrict__ X, long xbstride,
                      const float* __restrict__ scsh, float* __restrict__ out, long ocoff){
  long i = (long)blockIdx.x*256 + threadIdx.x;  // 1,048,576 threads
  long e = i*8;
  int b = (int)(e >> 19);
  int rem = (int)(e & 524287);                  // c*2048 + m
  int c = rem >> 11;
  f16x8 hv = *(const f16x8*)(h1 + e);
  const float* xb = X + (long)b*xbstride + rem;
  float4 xr0 = *(const float4*)xb;
  float4 xr1 = *(const float4*)(xb + 4);
  float sc = scsh[c], sh = scsh[256+c];
  float4 o0, o1;
  o0.x = xr0.x + fmaxf(fmaf((float)hv[0], sc, sh), 0.f);
  o0.y = xr0.y + fmaxf(fmaf((float)hv[1], sc, sh), 0.f);
  o0.z = xr0.z + fmaxf(fmaf((float)hv[2], sc, sh), 0.f);
  o0.w = xr0.w + fmaxf(fmaf((float)hv[3], sc, sh), 0.f);
  o1.x = xr1.x + fmaxf(fmaf((float)hv[4], sc, sh), 0.f);
  o1.y = xr1.y + fmaxf(fmaf((float)hv[5], sc, sh), 0.f);
  o1.z = xr1.z + fmaxf(fmaf((float)hv[6], sc, sh), 0.f);
  o1.w = xr1.w + fmaxf(fmaf((float)hv[7], sc, sh), 0.f);
  float* ob = out + (long)b*(512L*N_) + ocoff + rem;
  *(float4*)ob       = o0;
  *(float4*)(ob + 4) = o1;
}

// ---------------------------------------------------------------------------
extern "C" void kernel_launch(void* const* d_in, const int* in_sizes, int n_in,
                              void* d_out, int out_size, void* d_ws, size_t ws_size,
                              hipStream_t stream){
  (void)in_sizes; (void)n_in; (void)out_size; (void)ws_size;
  const float* x = (const float*)d_in[0];
  const float *Wf[2][4], *bv[2], *bt[2], *gm[2], *bb[2];
  for(int l=0;l<2;l++){
    int base = 1 + l*8;
    Wf[l][0]=(const float*)d_in[base+0];  // Wq
    Wf[l][1]=(const float*)d_in[base+1];  // Wk
    Wf[l][2]=(const float*)d_in[base+2];  // Wv
    bv[l]   =(const float*)d_in[base+3];
    Wf[l][3]=(const float*)d_in[base+4];  // Wt
    bt[l]   =(const float*)d_in[base+5];
    gm[l]   =(const float*)d_in[base+6];
    bb[l]   =(const float*)d_in[base+7];
  }
  char* ws = (char*)d_ws;
  size_t off = 0;
  auto alloc = [&](size_t bytes){ size_t o = off; off += (bytes + 255) & ~(size_t)255; return o; };
  size_t oXt = alloc((size_t)B_*N_*512*2);     // fp16 split x^T
  size_t oXq = alloc((size_t)B_*N_*256*2);     // fp16 split q [n][256]
  size_t oXk = alloc((size_t)B_*N_*256*2);     // fp16 split k [m][256]
  size_t oXv = alloc((size_t)B_*C_*N_*2);      // fp16 v [c][n]
  size_t oH0 = alloc((size_t)B_*N_*C_*2);      // fp16 h0^T [m][c]
  size_t oRo = alloc((size_t)B_*N_*4);         // f32 rowoff
  size_t oBn = alloc(2*512*4);                 // BN accum per layer
  size_t oSc = alloc(2*512*4);                 // BN scale/shift per layer
  size_t oW  = alloc((size_t)786432*2);        // fp16 split weights

  hipMemsetAsync(ws + oBn, 0, 2*512*4, stream);
  k_wconv<<<1536,256,0,stream>>>(Wf[0][0],Wf[0][1],Wf[0][2],Wf[0][3],
                                 Wf[1][0],Wf[1][1],Wf[1][2],Wf[1][3],
                                 (f16_t*)(ws+oW));
  float* dout = (float*)d_out;
  f16_t* H1 = (f16_t*)(ws + oXq);              // aliases Xq (dead when used)
  for(int l=0;l<2;l++){
    const float* Xl = l ? dout : x;
    long xbs = l ? 512L*N_ : 256L*N_;
    const f16_t* WqS = (const f16_t*)(ws+oW) + (size_t)l*393216;
    const f16_t* WkS = WqS + 65536;
    const f16_t* WvS = WqS + 131072;
    const f16_t* WtS = WqS + 262144;
    f16_t* XtS = (f16_t*)(ws+oXt);
    f16_t* Xq  = (f16_t*)(ws+oXq);
    f16_t* Xk  = (f16_t*)(ws+oXk);
    f16_t* Xv  = (f16_t*)(ws+oXv);
    f16_t* H0  = (f16_t*)(ws+oH0);
    float* Ro  = (float*)(ws+oRo);
    float* Bn  = (float*)(ws+oBn) + l*512;
    float* Sc  = (float*)(ws+oSc) + l*512;

    k_transpose<<<dim3(B_, N_/32, C_/64),256,0,stream>>>(Xl, xbs, XtS);
    // q: 32 m-tiles (LGX=5), 2 n-tiles -> 1024 blocks
    k_gemm3<5,1,0><<<1024,256,0,stream>>>(XtS, (long)N_*512, WqS, 0L,
                                          Xq, 256, (long)N_*256, nullptr);
    k_gemm3<5,1,0><<<1024,256,0,stream>>>(XtS, (long)N_*512, WkS, 0L,
                                          Xk, 256, (long)N_*256, nullptr);
    // v: 4 o-tiles (LGX=2), 32 n-tiles -> 2048 blocks
    k_gemm3<2,0,1><<<2048,256,0,stream>>>(WvS, 0L, XtS, (long)N_*512,
                                          Xv, N_, (long)C_*N_, bv[l]);
    k_rowstats<<<512,512,0,stream>>>(Xq, Xk, Ro);
    k_apply<<<512,256,0,stream>>>(Xq, Xk, Xv, Ro, Xl, xbs, H0);
    k_wt_bn<<<2048,256,0,stream>>>(WtS, H0, bt[l], H1, Bn);
    k_bnfin<<<1,256,0,stream>>>(Bn, gm[l], bb[l], Sc);
    k_out<<<4096,256,0,stream>>>(H1, Xl, xbs, Sc, dout, (long)l*C_*N_);
  }
}

// Round 10
// 1195.748 us; speedup vs baseline: 1.5955x; 1.3050x over previous
//
#include <hip/hip_runtime.h>

#define DI __device__ __forceinline__

typedef _Float16 f16_t;
typedef _Float16 f16x8 __attribute__((ext_vector_type(8)));
typedef float    f32x4 __attribute__((ext_vector_type(4)));

static_assert(sizeof(f16x8) == 16, "f16x8 must be 16B");

#define B_  16
#define C_  256
#define CH_ 128
#define N_  2048

DI f32x4 fzero(){ f32x4 z = {0.f,0.f,0.f,0.f}; return z; }
DI f16x8 ldg8(const f16_t* p){ return *(const f16x8*)p; }
DI f32x4 mfma16(f16x8 a, f16x8 b, f32x4 c){
  return __builtin_amdgcn_mfma_f32_16x16x32_f16(a, b, c, 0, 0, 0);
}
DI void split2(float v, f16_t& hi, f16_t& lo){
  hi = (f16_t)v; lo = (f16_t)(v - (float)hi);
}
// XCD-pair swizzle: blocks i≡x (mod 8) land on XCD x; give XCD x batches {2x,2x+1}
DI int swz_b(int i){ return ((i&7)<<1) | ((i>>3)&1); }

#define GLL16(src, dst) __builtin_amdgcn_global_load_lds( \
    (const __attribute__((address_space(1))) void*)(src), \
    (__attribute__((address_space(3))) void*)(dst), 16, 0, 0)

// ---------------------------------------------------------------------------
// Weight fp32 -> fp16 hi/lo split pack. Per layer: WqS[128][512] WkS[128][512]
// WvS[256][512] WtS[256][512] (cols 0..255 = hi, 256..511 = lo).
__global__ void k_wconv(const float* q1,const float* k1,const float* v1,const float* t1,
                        const float* q2,const float* k2,const float* v2,const float* t2,
                        f16_t* out){
  int i = blockIdx.x*256 + threadIdx.x;            // 0..393215
  int l = (i >= 196608) ? 1 : 0;
  int r = i - l*196608;
  const float* s; long dbase;
  if(r < 32768){ s = l? q2:q1; dbase = 0; }
  else if(r < 65536){ r -= 32768; s = l? k2:k1; dbase = 65536; }
  else if(r < 131072){ r -= 65536; s = l? v2:v1; dbase = 131072; }
  else { r -= 131072; s = l? t2:t1; dbase = 262144; }
  int o = r >> 8, c = r & 255;
  float v = s[o*256 + c];
  f16_t hi, lo; split2(v, hi, lo);
  f16_t* d = out + (long)l*393216 + dbase + (long)o*512;
  d[c] = hi; d[c+256] = lo;
}

// ---------------------------------------------------------------------------
// Transpose+split: XtS[b][n][512] = {hi(x[b][:,n]), lo}. grid (B, N/32, C/64)
__global__ void k_transpose(const float* __restrict__ X, long bstride,
                            f16_t* __restrict__ XtS){
  int b = blockIdx.x, n0 = blockIdx.y*32, c0 = blockIdx.z*64;
  __shared__ float tl[32][65];
  int t = threadIdx.x;
  int nn = t & 31, cr = t >> 5;                     // cr in 0..7
  const float* src = X + (long)b*bstride + n0 + nn;
  #pragma unroll
  for(int i=0;i<8;i++){
    int cc = cr + i*8;
    tl[nn][cc] = src[(long)(c0+cc)*N_];
  }
  __syncthreads();
  int n2 = t >> 3, cq = (t & 7)*8;
  __align__(16) f16_t hi8[8], lo8[8];
  #pragma unroll
  for(int j=0;j<8;j++) split2(tl[n2][cq+j], hi8[j], lo8[j]);
  f16_t* dst = XtS + ((long)b*N_ + n0 + n2)*512 + c0 + cq;
  *(f16x8*)dst         = *(f16x8*)hi8;
  *(f16x8*)(dst + 256) = *(f16x8*)lo8;
}

// ---------------------------------------------------------------------------
// 3-term split GEMM: out[row][col] = sum_k (Ah+Al)[row][k]*(Bh+Bl)[col][k]
// (drops Al*Bl). A,B rows are 512-wide hi|lo, K=256. 64x64 tile, 4 waves.
// 1-D grid, XCD-pair swizzle; m-tile = (r & (2^LGX-1)), n-tile = r >> LGX.
template<int LGX, int SPLIT_OUT, int BIAS>
__global__ __launch_bounds__(256) void k_gemm3(
    const f16_t* __restrict__ A, long sA,
    const f16_t* __restrict__ Bt, long sB,
    f16_t* __restrict__ out, int ldo, long sO,
    const float* __restrict__ bias)
{
  int i = blockIdx.x;
  int b = swz_b(i);
  int r = i>>4;
  int m0 = (r & ((1<<LGX)-1))*64, n0 = (r >> LGX)*64;
  int t = threadIdx.x, w = t>>6, l = t&63, lr = l&15, lg = l>>4;
  const f16_t* Ab = A + (long)b*sA + (long)(m0 + w*16 + lr)*512;
  const f16_t* Bb = Bt + (long)b*sB;
  f32x4 acc[4];
  #pragma unroll
  for(int i2=0;i2<4;i2++) acc[i2] = fzero();
  for(int k=0;k<256;k+=32){
    f16x8 ah = ldg8(Ab + k + lg*8);
    f16x8 al = ldg8(Ab + 256 + k + lg*8);
    #pragma unroll
    for(int ns=0;ns<4;ns++){
      const f16_t* brow = Bb + (long)(n0 + ns*16 + lr)*512;
      f16x8 bh = ldg8(brow + k + lg*8);
      f16x8 bl = ldg8(brow + 256 + k + lg*8);
      acc[ns] = mfma16(ah, bh, acc[ns]);
      acc[ns] = mfma16(ah, bl, acc[ns]);
      acc[ns] = mfma16(al, bh, acc[ns]);
    }
  }
  f16_t* ob = out + (long)b*sO;
  #pragma unroll
  for(int ns=0;ns<4;ns++){
    #pragma unroll
    for(int j=0;j<4;j++){
      int row = m0 + w*16 + lg*4 + j;
      int col = n0 + ns*16 + lr;
      float v = acc[ns][j];
      if(BIAS) v += bias[row];
      if(SPLIT_OUT){
        f16_t hi, lo; split2(v, hi, lo);
        ob[(long)row*ldo + col]       = hi;
        ob[(long)row*ldo + col + 128] = lo;
      } else {
        ob[(long)row*ldo + col] = (f16_t)v;
      }
    }
  }
}

// ---------------------------------------------------------------------------
// Pass 1: rowoff[b][n] = rowmax + ln(sum exp). 8 waves; group g = w>>2 handles
// m in [g*1024,(g+1)*1024); LDS merge at end. 1-D grid 512, XCD swizzle.
__global__ __launch_bounds__(512,4) void k_rowstats(
    const f16_t* __restrict__ xqS, const f16_t* __restrict__ xkS,
    float* __restrict__ rowoff)
{
  const int i = blockIdx.x;
  const int b = swz_b(i);
  const int n0 = (i>>4)*64;
  const int t = threadIdx.x, w = t>>6, l = t&63, lr = l&15, lg = l>>4;
  const int g = w>>2, wg = w&3;
  __shared__ float RS[256];                  // R[2][64] | S[2][64]
  const f16_t* qp = xqS + ((long)b*N_ + n0 + wg*16 + lr)*256;
  f16x8 bqh[4], bql[4];
  #pragma unroll
  for(int k=0;k<4;k++){
    bqh[k] = ldg8(qp + k*32 + lg*8);
    bql[k] = ldg8(qp + 128 + k*32 + lg*8);
  }
  const f16_t* kb = xkS + (long)b*N_*256;
  float rmax = -3e38f, rsum = 0.f;
  for(int m0=g*1024; m0<g*1024+1024; m0+=64){
    #pragma unroll
    for(int s=0;s<4;s++){
      const f16_t* kr = kb + (long)(m0 + s*16 + lr)*256;
      f16x8 ah[4], al_[4];
      #pragma unroll
      for(int k=0;k<4;k++){
        ah[k]  = ldg8(kr + k*32 + lg*8);
        al_[k] = ldg8(kr + 128 + k*32 + lg*8);
      }
      f32x4 a1 = fzero(), a2 = fzero(), a3 = fzero();   // 3 independent chains
      #pragma unroll
      for(int k=0;k<4;k++) a1 = mfma16(ah[k],  bqh[k], a1);
      #pragma unroll
      for(int k=0;k<4;k++) a2 = mfma16(ah[k],  bql[k], a2);
      #pragma unroll
      for(int k=0;k<4;k++) a3 = mfma16(al_[k], bqh[k], a3);
      f32x4 acc = (a1 + a2) + a3;
      float vm = fmaxf(fmaxf(acc[0],acc[1]), fmaxf(acc[2],acc[3]));
      float nm = fmaxf(rmax, vm);
      rsum = rsum*__expf(rmax-nm)
           + __expf(acc[0]-nm)+__expf(acc[1]-nm)+__expf(acc[2]-nm)+__expf(acc[3]-nm);
      rmax = nm;
    }
  }
  #pragma unroll
  for(int off=16; off<64; off<<=1){
    float om = __shfl_xor(rmax, off, 64);
    float os = __shfl_xor(rsum, off, 64);
    float nm = fmaxf(rmax, om);
    rsum = rsum*__expf(rmax-nm) + os*__expf(om-nm);
    rmax = nm;
  }
  if(lg==0){
    RS[g*64 + wg*16 + lr]       = rmax;
    RS[128 + g*64 + wg*16 + lr] = rsum;
  }
  __syncthreads();
  if(g==0 && lg==0){
    int idx = wg*16 + lr;
    float m0v = RS[idx],     m1v = RS[64+idx];
    float s0  = RS[128+idx], s1  = RS[192+idx];
    float mm = fmaxf(m0v, m1v);
    float ss = s0*__expf(m0v-mm) + s1*__expf(m1v-mm);
    rowoff[(long)b*N_ + n0 + idx] = mm + __logf(ss);
  }
}

// ---------------------------------------------------------------------------
// Pass 2 (flash-col, pipelined): q AND V staged to LDS via global_load_lds
// (double-buffered, counted vmcnt(8) -> loads span barriers, T3/T4 pattern).
// Global sources pre-swizzled so ds_reads are ~conflict-free (rule #21).
// Swapped-operand energy, lane's 8 P values = PV B-frag. Defer-max THR=8.
// LDS: q 2x16K | V 2x16K | ro 8K = 72KB dynamic. 1-D grid 512, XCD swizzle.
__global__ __launch_bounds__(256) void k_apply(
    const f16_t* __restrict__ xqS, const f16_t* __restrict__ xkS,
    const f16_t* __restrict__ xv, const float* __restrict__ rowoff,
    const float* __restrict__ X, long xbstride, f16_t* __restrict__ h0T)
{
  extern __shared__ __align__(16) char smem[];
  // layout: qbuf[2] @ 0,16384 ; vbuf[2] @ 32768,49152 ; ro_s @ 65536
  const int bi = blockIdx.x;
  const int b = swz_b(bi);
  const int m0 = (bi>>4)*64;
  const int t = threadIdx.x, w = t>>6, l = t&63, lr = l&15, lg = l>>4;
  float* ro_s = (float*)(smem + 65536);
  {
    const float* rob = rowoff + (long)b*N_;
    *(f32x4*)(ro_s + t*4)        = *(const f32x4*)(rob + t*4);
    *(f32x4*)(ro_s + t*4 + 1024) = *(const f32x4*)(rob + t*4 + 1024);
  }

  const f16_t* akp = xkS + ((long)b*N_ + m0 + w*16 + lr)*256;
  f16x8 akh[4], akl[4];
  #pragma unroll
  for(int k=0;k<4;k++){
    akh[k] = ldg8(akp + k*32 + lg*8);
    akl[k] = ldg8(akp + 128 + k*32 + lg*8);
  }

  const f16_t* xqb = xqS + (long)b*N_*256;
  const f16_t* xvb = xv + (long)b*C_*N_;
  const int qperm = ((lr>>2)*8 + (lr&3));                // + s2*4

  // staging geometry (per wave w, round r, lane l):
  //  q: idx=(r*4+w)*64+l -> row=(r*4+w)*2+(l>>5), slot=l&31;
  //     global granule = slot ^ ((row&3)|(((row>>3)&3)<<2))
  //  V: idx -> c=(r*4+w)*16+(l>>2), slot=l&3; global granule = slot ^ (c&3)
  const int qrow_off = (l>>5), qslot = l&31;
  const int vc_off = (l>>2), vslot = l&3;

  #define STAGE(nn, nxtbuf) do {                                              \
    char* qd = smem + (nxtbuf)*16384;                                         \
    char* vd = smem + 32768 + (nxtbuf)*16384;                                 \
    _Pragma("unroll")                                                         \
    for(int r=0;r<4;r++){                                                     \
      int qrow = (r*4+w)*2 + qrow_off;                                        \
      int qsw  = (qrow&3) | (((qrow>>3)&3)<<2);                               \
      const f16_t* qsrc = xqb + (long)((nn) + qrow)*256 + ((qslot ^ qsw)*8);  \
      GLL16(qsrc, qd + (r*4+w)*1024);                                         \
      int vc = (r*4+w)*16 + vc_off;                                           \
      const f16_t* vsrc2 = xvb + (long)vc*N_ + (nn) + ((vslot ^ (vc&3))*8);   \
      GLL16(vsrc2, vd + (r*4+w)*1024);                                        \
    }                                                                         \
  } while(0)

  f32x4 y[16];
  #pragma unroll
  for(int i2=0;i2<16;i2++) y[i2] = fzero();
  float cs = 0.f, cm = -3e38f;

  __syncthreads();                 // ro_s ready (drains everything, count=0)
  STAGE(0, 0);                     // chunk 0 -> buffers 0

  const int vsl = (lg ^ (lr&3)) << 4;    // per-lane V read swizzle (bytes)

  #pragma unroll 1
  for(int i=0; i<64; i++){
    const int cur = i&1, nxt = cur^1;
    const int n0 = i*32;
    const int nn = (i<63) ? (n0+32) : 0;
    STAGE(nn, nxt);                              // 8 gll ops, chunk i+1
    asm volatile("s_waitcnt vmcnt(8)" ::: "memory");  // chunk i landed
    asm volatile("s_barrier" ::: "memory");           // head
    const char* qb = smem + cur*16384;
    const char* vb = smem + 32768 + cur*16384;
    // ---- energies from q LDS ----
    float g[2][4];
    #pragma unroll
    for(int s2=0;s2<2;s2++){
      const int rl = qperm + s2*4;
      const char* qrow = qb + rl*512;
      f16x8 qh[4], ql[4];
      #pragma unroll
      for(int k=0;k<4;k++){
        qh[k] = *(const f16x8*)(qrow + (((4*k + lg) ^ lr)<<4));
        ql[k] = *(const f16x8*)(qrow + 256 + (((4*k + lg) ^ lr)<<4));
      }
      f32x4 e1 = fzero(), e2 = fzero(), e3 = fzero();
      #pragma unroll
      for(int k=0;k<4;k++) e1 = mfma16(qh[k], akh[k], e1);
      #pragma unroll
      for(int k=0;k<4;k++) e2 = mfma16(ql[k], akh[k], e2);
      #pragma unroll
      for(int k=0;k<4;k++) e3 = mfma16(qh[k], akl[k], e3);
      f32x4 e = (e1 + e2) + e3;
      f32x4 ro4 = *(const f32x4*)(ro_s + n0 + lg*8 + s2*4);
      #pragma unroll
      for(int j=0;j<4;j++) g[s2][j] = e[j] - ro4[j];
    }
    // ---- per-column (m=lr) chunk max: in-lane 8, then 2 shfl across lg ----
    float v = fmaxf(fmaxf(fmaxf(g[0][0],g[0][1]), fmaxf(g[0][2],g[0][3])),
                    fmaxf(fmaxf(g[1][0],g[1][1]), fmaxf(g[1][2],g[1][3])));
    v = fmaxf(v, __shfl_xor(v, 16, 64));
    v = fmaxf(v, __shfl_xor(v, 32, 64));
    bool need = v > cm + 8.f;
    float fj = need ? __expf(cm - v) : 1.f;
    if(need) cm = v;
    cs *= fj;
    // ---- P (fp16) in-register = PV B-frag; colsum from SAME rounded values
    __align__(16) f16_t pv[8];
    #pragma unroll
    for(int s2=0;s2<2;s2++){
      #pragma unroll
      for(int j=0;j<4;j++){
        float p = __expf(g[s2][j] - cm);
        f16_t pb = (f16_t)p;
        cs += (float)pb;
        pv[s2*4+j] = pb;
      }
    }
    f16x8 pfrag = *(const f16x8*)pv;
    if(__any(need)){
      #pragma unroll
      for(int cf=0;cf<16;cf++){
        #pragma unroll
        for(int j2=0;j2<4;j2++) y[cf][j2] *= fj;
      }
    }
    // ---- PV from V LDS: y[cf] covers c = cf*16 + lg*4 + j, m = lr ----
    #pragma unroll
    for(int cf=0;cf<16;cf++){
      f16x8 av = *(const f16x8*)(vb + (cf*16 + lr)*64 + vsl);
      y[cf] = mfma16(av, pfrag, y[cf]);
    }
    asm volatile("s_barrier" ::: "memory");           // tail
  }

  // colsum across the 4 lg lane-groups (butterfly -> all lanes)
  cs += __shfl_xor(cs, 16, 64);
  cs += __shfl_xor(cs, 32, 64);
  float inv = 1.f/(1e-9f*__expf(-cm) + cs);

  // ---- two-half epilogue: x_r -> H (16KB @ vbuf[1]), h0 = X - x_r -> h0T ----
  f16_t* H = (f16_t*)(smem + 49152);
  const int mq = t&63, cq = t>>6;
  const float* Xb = X + (long)b*xbstride + m0;
  uint4* dstb = (uint4*)(h0T + ((long)b*N_ + m0)*C_);
  #pragma unroll
  for(int half=0; half<2; half++){
    #pragma unroll
    for(int cf8=0; cf8<8; cf8++){
      int cf = half*8 + cf8;
      #pragma unroll
      for(int j=0;j<4;j++){
        int cl = cf8*16 + lg*4 + j;                 // 0..127
        int m  = w*16 + lr;
        *(f16_t*)((char*)H + m*256 + ((((cl>>3) ^ (m&7))<<4) | ((cl&7)<<1)))
          = (f16_t)(y[cf][j]*inv);
      }
    }
    __syncthreads();
    #pragma unroll 4
    for(int ci=0; ci<32; ci++){
      int cl = cq*32 + ci;
      int c  = half*128 + cl;
      f16_t* hp = (f16_t*)((char*)H + mq*256 + ((((cl>>3) ^ (mq&7))<<4) | ((cl&7)<<1)));
      *hp = (f16_t)(Xb[(long)c*N_ + mq] - (float)*hp);
    }
    __syncthreads();
    {
      const uint4* src = (const uint4*)H;
      for(int i2=t;i2<1024;i2+=256){
        int row = i2>>4, slot = i2&15;
        dstb[row*32 + half*16 + slot] = src[(i2 & ~15) | (slot ^ (row&7))];
      }
    }
    __syncthreads();
  }
  #undef STAGE
}

// ---------------------------------------------------------------------------
// h1[b][o][m] = Wt @ h0 + bt (2-term: Wt hi+lo), fp16 out + BN partial sums.
// 1-D grid 2048, XCD swizzle.
__global__ __launch_bounds__(256) void k_wt_bn(
    const f16_t* __restrict__ WtS, const f16_t* __restrict__ h0T,
    const float* __restrict__ bt,
    f16_t* __restrict__ h1, float* __restrict__ bnacc)
{
  int i = blockIdx.x;
  int b = swz_b(i);
  int r = i>>4;
  int o0 = (r&3)*64, m0 = (r>>2)*64;
  int t=threadIdx.x, w=t>>6, l=t&63, lr=l&15, lg=l>>4;
  const f16_t* Arow = WtS + (long)(o0 + w*16 + lr)*512;
  const f16_t* Bb = h0T + (long)b*N_*C_;
  f32x4 acc[4];
  #pragma unroll
  for(int i2=0;i2<4;i2++) acc[i2] = fzero();
  for(int k=0;k<C_;k+=32){
    f16x8 afh = ldg8(Arow + k + lg*8);
    f16x8 afl = ldg8(Arow + 256 + k + lg*8);
    #pragma unroll
    for(int ms=0;ms<4;ms++){
      f16x8 bf_ = ldg8(Bb + (long)(m0 + ms*16 + lr)*C_ + k + lg*8);
      acc[ms] = mfma16(afh, bf_, acc[ms]);
      acc[ms] = mfma16(afl, bf_, acc[ms]);
    }
  }
  float s1[4]={0.f,0.f,0.f,0.f}, s2v[4]={0.f,0.f,0.f,0.f};
  f16_t* h1b = h1 + (long)b*C_*N_;
  #pragma unroll
  for(int j=0;j<4;j++){
    int o = o0 + w*16 + lg*4 + j;
    float bias = bt[o];
    #pragma unroll
    for(int ms=0;ms<4;ms++){
      float v = acc[ms][j] + bias;
      h1b[(long)o*N_ + m0 + ms*16 + lr] = (f16_t)v;
      s1[j] += v; s2v[j] += v*v;
    }
  }
  #pragma unroll
  for(int off=1; off<16; off<<=1){
    #pragma unroll
    for(int j=0;j<4;j++){ s1[j]+=__shfl_xor(s1[j],off,64); s2v[j]+=__shfl_xor(s2v[j],off,64); }
  }
  if(lr==0){
    #pragma unroll
    for(int j=0;j<4;j++){
      int o = o0 + w*16 + lg*4 + j;
      atomicAdd(&bnacc[o], s1[j]);
      atomicAdd(&bnacc[256+o], s2v[j]);
    }
  }
}

// BN finalize -> scale/shift
__global__ void k_bnfin(const float* __restrict__ bnacc, const float* __restrict__ gamma,
                        const float* __restrict__ beta, float* __restrict__ scsh){
  int o = threadIdx.x;
  float mean = bnacc[o] * (1.f/32768.f);
  float var  = bnacc[256+o] * (1.f/32768.f) - mean*mean;
  float sc = gamma[o] * rsqrtf(var + 1e-5f);
  scsh[o] = sc;
  scsh[256+o] = beta[o] - mean*sc;
}

// out = X + relu(h1*sc + sh); writes one 256-channel half of d_out. 8 elems/thr.
__global__ void k_out(const f16_t* __restrict__ h1, const float* __restrict__ X, long xbstride,
                      const float* __restrict__ scsh, float* __restrict__ out, long ocoff){
  long i = (long)blockIdx.x*256 + threadIdx.x;  // 1,048,576 threads
  long e = i*8;
  int b = (int)(e >> 19);
  int rem = (int)(e & 524287);                  // c*2048 + m
  int c = rem >> 11;
  f16x8 hv = *(const f16x8*)(h1 + e);
  const float* xb = X + (long)b*xbstride + rem;
  float4 xr0 = *(const float4*)xb;
  float4 xr1 = *(const float4*)(xb + 4);
  float sc = scsh[c], sh = scsh[256+c];
  float4 o0, o1;
  o0.x = xr0.x + fmaxf(fmaf((float)hv[0], sc, sh), 0.f);
  o0.y = xr0.y + fmaxf(fmaf((float)hv[1], sc, sh), 0.f);
  o0.z = xr0.z + fmaxf(fmaf((float)hv[2], sc, sh), 0.f);
  o0.w = xr0.w + fmaxf(fmaf((float)hv[3], sc, sh), 0.f);
  o1.x = xr1.x + fmaxf(fmaf((float)hv[4], sc, sh), 0.f);
  o1.y = xr1.y + fmaxf(fmaf((float)hv[5], sc, sh), 0.f);
  o1.z = xr1.z + fmaxf(fmaf((float)hv[6], sc, sh), 0.f);
  o1.w = xr1.w + fmaxf(fmaf((float)hv[7], sc, sh), 0.f);
  float* ob = out + (long)b*(512L*N_) + ocoff + rem;
  *(float4*)ob       = o0;
  *(float4*)(ob + 4) = o1;
}

// ---------------------------------------------------------------------------
extern "C" void kernel_launch(void* const* d_in, const int* in_sizes, int n_in,
                              void* d_out, int out_size, void* d_ws, size_t ws_size,
                              hipStream_t stream){
  (void)in_sizes; (void)n_in; (void)out_size; (void)ws_size;
  const float* x = (const float*)d_in[0];
  const float *Wf[2][4], *bv[2], *bt[2], *gm[2], *bb[2];
  for(int l=0;l<2;l++){
    int base = 1 + l*8;
    Wf[l][0]=(const float*)d_in[base+0];  // Wq
    Wf[l][1]=(const float*)d_in[base+1];  // Wk
    Wf[l][2]=(const float*)d_in[base+2];  // Wv
    bv[l]   =(const float*)d_in[base+3];
    Wf[l][3]=(const float*)d_in[base+4];  // Wt
    bt[l]   =(const float*)d_in[base+5];
    gm[l]   =(const float*)d_in[base+6];
    bb[l]   =(const float*)d_in[base+7];
  }
  char* ws = (char*)d_ws;
  size_t off = 0;
  auto alloc = [&](size_t bytes){ size_t o = off; off += (bytes + 255) & ~(size_t)255; return o; };
  size_t oXt = alloc((size_t)B_*N_*512*2);     // fp16 split x^T
  size_t oXq = alloc((size_t)B_*N_*256*2);     // fp16 split q [n][256]
  size_t oXk = alloc((size_t)B_*N_*256*2);     // fp16 split k [m][256]
  size_t oXv = alloc((size_t)B_*C_*N_*2);      // fp16 v [c][n]
  size_t oH0 = alloc((size_t)B_*N_*C_*2);      // fp16 h0^T [m][c]
  size_t oRo = alloc((size_t)B_*N_*4);         // f32 rowoff
  size_t oBn = alloc(2*512*4);                 // BN accum per layer
  size_t oSc = alloc(2*512*4);                 // BN scale/shift per layer
  size_t oW  = alloc((size_t)786432*2);        // fp16 split weights

  hipMemsetAsync(ws + oBn, 0, 2*512*4, stream);
  k_wconv<<<1536,256,0,stream>>>(Wf[0][0],Wf[0][1],Wf[0][2],Wf[0][3],
                                 Wf[1][0],Wf[1][1],Wf[1][2],Wf[1][3],
                                 (f16_t*)(ws+oW));
  float* dout = (float*)d_out;
  f16_t* H1 = (f16_t*)(ws + oXq);              // aliases Xq (dead when used)
  for(int l=0;l<2;l++){
    const float* Xl = l ? dout : x;
    long xbs = l ? 512L*N_ : 256L*N_;
    const f16_t* WqS = (const f16_t*)(ws+oW) + (size_t)l*393216;
    const f16_t* WkS = WqS + 65536;
    const f16_t* WvS = WqS + 131072;
    const f16_t* WtS = WqS + 262144;
    f16_t* XtS = (f16_t*)(ws+oXt);
    f16_t* Xq  = (f16_t*)(ws+oXq);
    f16_t* Xk  = (f16_t*)(ws+oXk);
    f16_t* Xv  = (f16_t*)(ws+oXv);
    f16_t* H0  = (f16_t*)(ws+oH0);
    float* Ro  = (float*)(ws+oRo);
    float* Bn  = (float*)(ws+oBn) + l*512;
    float* Sc  = (float*)(ws+oSc) + l*512;

    k_transpose<<<dim3(B_, N_/32, C_/64),256,0,stream>>>(Xl, xbs, XtS);
    k_gemm3<5,1,0><<<1024,256,0,stream>>>(XtS, (long)N_*512, WqS, 0L,
                                          Xq, 256, (long)N_*256, nullptr);
    k_gemm3<5,1,0><<<1024,256,0,stream>>>(XtS, (long)N_*512, WkS, 0L,
                                          Xk, 256, (long)N_*256, nullptr);
    k_gemm3<2,0,1><<<2048,256,0,stream>>>(WvS, 0L, XtS, (long)N_*512,
                                          Xv, N_, (long)C_*N_, bv[l]);
    k_rowstats<<<512,512,0,stream>>>(Xq, Xk, Ro);
    k_apply<<<512,256,73728,stream>>>(Xq, Xk, Xv, Ro, Xl, xbs, H0);
    k_wt_bn<<<2048,256,0,stream>>>(WtS, H0, bt[l], H1, Bn);
    k_bnfin<<<1,256,0,stream>>>(Bn, gm[l], bb[l], Sc);
    k_out<<<4096,256,0,stream>>>(H1, Xl, xbs, Sc, dout, (long)l*C_*N_);
  }
}

// Round 11
// 854.165 us; speedup vs baseline: 2.2336x; 1.3999x over previous
//
#include <hip/hip_runtime.h>

#define DI __device__ __forceinline__

typedef _Float16 f16_t;
typedef _Float16 f16x8 __attribute__((ext_vector_type(8)));
typedef float    f32x4 __attribute__((ext_vector_type(4)));

static_assert(sizeof(f16x8) == 16, "f16x8 must be 16B");

#define B_  16
#define C_  256
#define CH_ 128
#define N_  2048

DI f32x4 fzero(){ f32x4 z = {0.f,0.f,0.f,0.f}; return z; }
DI f16x8 ldg8(const f16_t* p){ return *(const f16x8*)p; }
DI f32x4 mfma16(f16x8 a, f16x8 b, f32x4 c){
  return __builtin_amdgcn_mfma_f32_16x16x32_f16(a, b, c, 0, 0, 0);
}
DI void split2(float v, f16_t& hi, f16_t& lo){
  hi = (f16_t)v; lo = (f16_t)(v - (float)hi);
}
// XCD-pair swizzle: blocks i≡x (mod 8) land on XCD x; give XCD x batches {2x,2x+1}
DI int swz_b(int i){ return ((i&7)<<1) | ((i>>3)&1); }

#define GLL16(src, dst) __builtin_amdgcn_global_load_lds( \
    (const __attribute__((address_space(1))) void*)(src), \
    (__attribute__((address_space(3))) void*)(dst), 16, 0, 0)

// ---------------------------------------------------------------------------
// Weight fp32 -> fp16 hi/lo split pack. Per layer: WqS[128][512] WkS[128][512]
// WvS[256][512] WtS[256][512] (cols 0..255 = hi, 256..511 = lo).
__global__ void k_wconv(const float* q1,const float* k1,const float* v1,const float* t1,
                        const float* q2,const float* k2,const float* v2,const float* t2,
                        f16_t* out){
  int i = blockIdx.x*256 + threadIdx.x;            // 0..393215
  int l = (i >= 196608) ? 1 : 0;
  int r = i - l*196608;
  const float* s; long dbase;
  if(r < 32768){ s = l? q2:q1; dbase = 0; }
  else if(r < 65536){ r -= 32768; s = l? k2:k1; dbase = 65536; }
  else if(r < 131072){ r -= 65536; s = l? v2:v1; dbase = 131072; }
  else { r -= 131072; s = l? t2:t1; dbase = 262144; }
  int o = r >> 8, c = r & 255;
  float v = s[o*256 + c];
  f16_t hi, lo; split2(v, hi, lo);
  f16_t* d = out + (long)l*393216 + dbase + (long)o*512;
  d[c] = hi; d[c+256] = lo;
}

// ---------------------------------------------------------------------------
// Transpose+split: XtS[b][n][512] = {hi(x[b][:,n]), lo}. grid (B, N/32, C/64)
__global__ void k_transpose(const float* __restrict__ X, long bstride,
                            f16_t* __restrict__ XtS){
  int b = blockIdx.x, n0 = blockIdx.y*32, c0 = blockIdx.z*64;
  __shared__ float tl[32][65];
  int t = threadIdx.x;
  int nn = t & 31, cr = t >> 5;                     // cr in 0..7
  const float* src = X + (long)b*bstride + n0 + nn;
  #pragma unroll
  for(int i=0;i<8;i++){
    int cc = cr + i*8;
    tl[nn][cc] = src[(long)(c0+cc)*N_];
  }
  __syncthreads();
  int n2 = t >> 3, cq = (t & 7)*8;
  __align__(16) f16_t hi8[8], lo8[8];
  #pragma unroll
  for(int j=0;j<8;j++) split2(tl[n2][cq+j], hi8[j], lo8[j]);
  f16_t* dst = XtS + ((long)b*N_ + n0 + n2)*512 + c0 + cq;
  *(f16x8*)dst         = *(f16x8*)hi8;
  *(f16x8*)(dst + 256) = *(f16x8*)lo8;
}

// ---------------------------------------------------------------------------
// 3-term split GEMM: out[row][col] = sum_k (Ah+Al)[row][k]*(Bh+Bl)[col][k]
// (drops Al*Bl). A,B rows are 512-wide hi|lo, K=256. 64x64 tile, 4 waves.
// 1-D grid, XCD-pair swizzle; m-tile = (r & (2^LGX-1)), n-tile = r >> LGX.
template<int LGX, int SPLIT_OUT, int BIAS>
__global__ __launch_bounds__(256) void k_gemm3(
    const f16_t* __restrict__ A, long sA,
    const f16_t* __restrict__ Bt, long sB,
    f16_t* __restrict__ out, int ldo, long sO,
    const float* __restrict__ bias)
{
  int i = blockIdx.x;
  int b = swz_b(i);
  int r = i>>4;
  int m0 = (r & ((1<<LGX)-1))*64, n0 = (r >> LGX)*64;
  int t = threadIdx.x, w = t>>6, l = t&63, lr = l&15, lg = l>>4;
  const f16_t* Ab = A + (long)b*sA + (long)(m0 + w*16 + lr)*512;
  const f16_t* Bb = Bt + (long)b*sB;
  f32x4 acc[4];
  #pragma unroll
  for(int i2=0;i2<4;i2++) acc[i2] = fzero();
  for(int k=0;k<256;k+=32){
    f16x8 ah = ldg8(Ab + k + lg*8);
    f16x8 al = ldg8(Ab + 256 + k + lg*8);
    #pragma unroll
    for(int ns=0;ns<4;ns++){
      const f16_t* brow = Bb + (long)(n0 + ns*16 + lr)*512;
      f16x8 bh = ldg8(brow + k + lg*8);
      f16x8 bl = ldg8(brow + 256 + k + lg*8);
      acc[ns] = mfma16(ah, bh, acc[ns]);
      acc[ns] = mfma16(ah, bl, acc[ns]);
      acc[ns] = mfma16(al, bh, acc[ns]);
    }
  }
  f16_t* ob = out + (long)b*sO;
  #pragma unroll
  for(int ns=0;ns<4;ns++){
    #pragma unroll
    for(int j=0;j<4;j++){
      int row = m0 + w*16 + lg*4 + j;
      int col = n0 + ns*16 + lr;
      float v = acc[ns][j];
      if(BIAS) v += bias[row];
      if(SPLIT_OUT){
        f16_t hi, lo; split2(v, hi, lo);
        ob[(long)row*ldo + col]       = hi;
        ob[(long)row*ldo + col + 128] = lo;
      } else {
        ob[(long)row*ldo + col] = (f16_t)v;
      }
    }
  }
}

// ---------------------------------------------------------------------------
// Pass 1 (pipelined): rowoff[b][n] = rowmax + ln(sum exp). 4 waves; each wave
// owns 16 n-rows (n = n0 + w*16 + lr) and scans ALL m. K chunk (32 rows)
// staged to LDS via global_load_lds, double-buffered, counted vmcnt(4) so
// chunk i+1's loads stay in flight across chunk-i compute (T3/T4). LDS granule
// g of row r holds global granule g^(r&15) (involution swizzle, rule #21).
// LDS 2x16KB. 1-D grid 512, XCD swizzle.
__global__ __launch_bounds__(256) void k_rowstats(
    const f16_t* __restrict__ xqS, const f16_t* __restrict__ xkS,
    float* __restrict__ rowoff)
{
  extern __shared__ __align__(16) char smem[];     // kbuf[2] @ 0, 16384
  const int bi = blockIdx.x;
  const int b = swz_b(bi);
  const int n0 = (bi>>4)*64;
  const int t = threadIdx.x, w = t>>6, l = t&63, lr = l&15, lg = l>>4;

  const f16_t* qp = xqS + ((long)b*N_ + n0 + w*16 + lr)*256;
  f16x8 bqh[4], bql[4];
  #pragma unroll
  for(int k=0;k<4;k++){
    bqh[k] = ldg8(qp + k*32 + lg*8);
    bql[k] = ldg8(qp + 128 + k*32 + lg*8);
  }
  const f16_t* kb = xkS + (long)b*N_*256;

  // staging geometry: lane covers local row (r*4+w)*2 + (l>>5), granule l&31
  const int krow_off = l>>5, kslot = l&31;
  #define KSTAGE(mm, buf) do {                                                \
    char* kd = smem + (buf)*16384;                                            \
    _Pragma("unroll")                                                         \
    for(int r=0;r<4;r++){                                                     \
      int row = (r*4+w)*2 + krow_off;                                         \
      const f16_t* ksrc = kb + (long)((mm) + row)*256 + ((kslot ^ (row&15))*8);\
      GLL16(ksrc, kd + (r*4+w)*1024);                                         \
    }                                                                         \
  } while(0)

  float rmax = -3e38f, rsum = 0.f;
  KSTAGE(0, 0);

  #pragma unroll 1
  for(int i=0; i<64; i++){
    const int cur = i&1, nxt = cur^1;
    const int mm = (i<63) ? (i+1)*32 : 0;
    KSTAGE(mm, nxt);                                 // 4 gll ops, chunk i+1
    asm volatile("s_waitcnt vmcnt(4)" ::: "memory"); // chunk i landed
    asm volatile("s_barrier" ::: "memory");
    const char* kbuf = smem + cur*16384;
    #pragma unroll
    for(int s=0;s<2;s++){
      const char* krow = kbuf + (s*16 + lr)*512;     // sw(row) = lr
      f16x8 ah[4], al_[4];
      #pragma unroll
      for(int k=0;k<4;k++){
        ah[k]  = *(const f16x8*)(krow + ((((4*k+lg) ^ lr))<<4));
        al_[k] = *(const f16x8*)(krow + ((16 + (((4*k+lg)) ^ lr))<<4));
      }
      f32x4 a1 = fzero(), a2 = fzero(), a3 = fzero();
      #pragma unroll
      for(int k=0;k<4;k++) a1 = mfma16(ah[k],  bqh[k], a1);
      #pragma unroll
      for(int k=0;k<4;k++) a2 = mfma16(ah[k],  bql[k], a2);
      #pragma unroll
      for(int k=0;k<4;k++) a3 = mfma16(al_[k], bqh[k], a3);
      f32x4 acc = (a1 + a2) + a3;
      float vm = fmaxf(fmaxf(acc[0],acc[1]), fmaxf(acc[2],acc[3]));
      float nm = fmaxf(rmax, vm);
      rsum = rsum*__expf(rmax-nm)
           + __expf(acc[0]-nm)+__expf(acc[1]-nm)+__expf(acc[2]-nm)+__expf(acc[3]-nm);
      rmax = nm;
    }
    asm volatile("s_barrier" ::: "memory");
  }
  #undef KSTAGE

  // merge the 4 lg-quarters (each lane has its n's stats over m%? -> lg split)
  #pragma unroll
  for(int off=16; off<64; off<<=1){
    float om = __shfl_xor(rmax, off, 64);
    float os = __shfl_xor(rsum, off, 64);
    float nm = fmaxf(rmax, om);
    rsum = rsum*__expf(rmax-nm) + os*__expf(om-nm);
    rmax = nm;
  }
  if(lg==0) rowoff[(long)b*N_ + n0 + w*16 + lr] = rmax + __logf(rsum);
}

// ---------------------------------------------------------------------------
// Pass 2 (flash-col, pipelined): q AND V staged to LDS via global_load_lds
// (double-buffered, counted vmcnt(8) -> loads span barriers, T3/T4 pattern).
// Global sources pre-swizzled so ds_reads are ~conflict-free (rule #21).
// Swapped-operand energy, lane's 8 P values = PV B-frag. Defer-max THR=8.
// LDS: q 2x16K | V 2x16K | ro 8K = 72KB dynamic. 1-D grid 512, XCD swizzle.
__global__ __launch_bounds__(256) void k_apply(
    const f16_t* __restrict__ xqS, const f16_t* __restrict__ xkS,
    const f16_t* __restrict__ xv, const float* __restrict__ rowoff,
    const float* __restrict__ X, long xbstride, f16_t* __restrict__ h0T)
{
  extern __shared__ __align__(16) char smem[];
  // layout: qbuf[2] @ 0,16384 ; vbuf[2] @ 32768,49152 ; ro_s @ 65536
  const int bi = blockIdx.x;
  const int b = swz_b(bi);
  const int m0 = (bi>>4)*64;
  const int t = threadIdx.x, w = t>>6, l = t&63, lr = l&15, lg = l>>4;
  float* ro_s = (float*)(smem + 65536);
  {
    const float* rob = rowoff + (long)b*N_;
    *(f32x4*)(ro_s + t*4)        = *(const f32x4*)(rob + t*4);
    *(f32x4*)(ro_s + t*4 + 1024) = *(const f32x4*)(rob + t*4 + 1024);
  }

  const f16_t* akp = xkS + ((long)b*N_ + m0 + w*16 + lr)*256;
  f16x8 akh[4], akl[4];
  #pragma unroll
  for(int k=0;k<4;k++){
    akh[k] = ldg8(akp + k*32 + lg*8);
    akl[k] = ldg8(akp + 128 + k*32 + lg*8);
  }

  const f16_t* xqb = xqS + (long)b*N_*256;
  const f16_t* xvb = xv + (long)b*C_*N_;
  const int qperm = ((lr>>2)*8 + (lr&3));                // + s2*4

  const int qrow_off = (l>>5), qslot = l&31;
  const int vc_off = (l>>2), vslot = l&3;

  #define STAGE(nn, nxtbuf) do {                                              \
    char* qd = smem + (nxtbuf)*16384;                                         \
    char* vd = smem + 32768 + (nxtbuf)*16384;                                 \
    _Pragma("unroll")                                                         \
    for(int r=0;r<4;r++){                                                     \
      int qrow = (r*4+w)*2 + qrow_off;                                        \
      int qsw  = (qrow&3) | (((qrow>>3)&3)<<2);                               \
      const f16_t* qsrc = xqb + (long)((nn) + qrow)*256 + ((qslot ^ qsw)*8);  \
      GLL16(qsrc, qd + (r*4+w)*1024);                                         \
      int vc = (r*4+w)*16 + vc_off;                                           \
      const f16_t* vsrc2 = xvb + (long)vc*N_ + (nn) + ((vslot ^ (vc&3))*8);   \
      GLL16(vsrc2, vd + (r*4+w)*1024);                                        \
    }                                                                         \
  } while(0)

  f32x4 y[16];
  #pragma unroll
  for(int i2=0;i2<16;i2++) y[i2] = fzero();
  float cs = 0.f, cm = -3e38f;

  __syncthreads();                 // ro_s ready (drains everything, count=0)
  STAGE(0, 0);                     // chunk 0 -> buffers 0

  const int vsl = (lg ^ (lr&3)) << 4;    // per-lane V read swizzle (bytes)

  #pragma unroll 1
  for(int i=0; i<64; i++){
    const int cur = i&1, nxt = cur^1;
    const int n0 = i*32;
    const int nn = (i<63) ? (n0+32) : 0;
    STAGE(nn, nxt);                              // 8 gll ops, chunk i+1
    asm volatile("s_waitcnt vmcnt(8)" ::: "memory");  // chunk i landed
    asm volatile("s_barrier" ::: "memory");           // head
    const char* qb = smem + cur*16384;
    const char* vb = smem + 32768 + cur*16384;
    // ---- energies from q LDS ----
    float g[2][4];
    #pragma unroll
    for(int s2=0;s2<2;s2++){
      const int rl = qperm + s2*4;
      const char* qrow = qb + rl*512;
      f16x8 qh[4], ql[4];
      #pragma unroll
      for(int k=0;k<4;k++){
        qh[k] = *(const f16x8*)(qrow + (((4*k + lg) ^ lr)<<4));
        ql[k] = *(const f16x8*)(qrow + 256 + (((4*k + lg) ^ lr)<<4));
      }
      f32x4 e1 = fzero(), e2 = fzero(), e3 = fzero();
      #pragma unroll
      for(int k=0;k<4;k++) e1 = mfma16(qh[k], akh[k], e1);
      #pragma unroll
      for(int k=0;k<4;k++) e2 = mfma16(ql[k], akh[k], e2);
      #pragma unroll
      for(int k=0;k<4;k++) e3 = mfma16(qh[k], akl[k], e3);
      f32x4 e = (e1 + e2) + e3;
      f32x4 ro4 = *(const f32x4*)(ro_s + n0 + lg*8 + s2*4);
      #pragma unroll
      for(int j=0;j<4;j++) g[s2][j] = e[j] - ro4[j];
    }
    // ---- per-column (m=lr) chunk max: in-lane 8, then 2 shfl across lg ----
    float v = fmaxf(fmaxf(fmaxf(g[0][0],g[0][1]), fmaxf(g[0][2],g[0][3])),
                    fmaxf(fmaxf(g[1][0],g[1][1]), fmaxf(g[1][2],g[1][3])));
    v = fmaxf(v, __shfl_xor(v, 16, 64));
    v = fmaxf(v, __shfl_xor(v, 32, 64));
    bool need = v > cm + 8.f;
    float fj = need ? __expf(cm - v) : 1.f;
    if(need) cm = v;
    cs *= fj;
    // ---- P (fp16) in-register = PV B-frag; colsum from SAME rounded values
    __align__(16) f16_t pv[8];
    #pragma unroll
    for(int s2=0;s2<2;s2++){
      #pragma unroll
      for(int j=0;j<4;j++){
        float p = __expf(g[s2][j] - cm);
        f16_t pb = (f16_t)p;
        cs += (float)pb;
        pv[s2*4+j] = pb;
      }
    }
    f16x8 pfrag = *(const f16x8*)pv;
    if(__any(need)){
      #pragma unroll
      for(int cf=0;cf<16;cf++){
        #pragma unroll
        for(int j2=0;j2<4;j2++) y[cf][j2] *= fj;
      }
    }
    // ---- PV from V LDS: y[cf] covers c = cf*16 + lg*4 + j, m = lr ----
    #pragma unroll
    for(int cf=0;cf<16;cf++){
      f16x8 av = *(const f16x8*)(vb + (cf*16 + lr)*64 + vsl);
      y[cf] = mfma16(av, pfrag, y[cf]);
    }
    asm volatile("s_barrier" ::: "memory");           // tail
  }

  // colsum across the 4 lg lane-groups (butterfly -> all lanes)
  cs += __shfl_xor(cs, 16, 64);
  cs += __shfl_xor(cs, 32, 64);
  float inv = 1.f/(1e-9f*__expf(-cm) + cs);

  // ---- two-half epilogue: x_r -> H (16KB @ vbuf[1]), h0 = X - x_r -> h0T ----
  f16_t* H = (f16_t*)(smem + 49152);
  const int mq = t&63, cq = t>>6;
  const float* Xb = X + (long)b*xbstride + m0;
  uint4* dstb = (uint4*)(h0T + ((long)b*N_ + m0)*C_);
  #pragma unroll
  for(int half=0; half<2; half++){
    #pragma unroll
    for(int cf8=0; cf8<8; cf8++){
      int cf = half*8 + cf8;
      #pragma unroll
      for(int j=0;j<4;j++){
        int cl = cf8*16 + lg*4 + j;                 // 0..127
        int m  = w*16 + lr;
        *(f16_t*)((char*)H + m*256 + ((((cl>>3) ^ (m&7))<<4) | ((cl&7)<<1)))
          = (f16_t)(y[cf][j]*inv);
      }
    }
    __syncthreads();
    #pragma unroll 4
    for(int ci=0; ci<32; ci++){
      int cl = cq*32 + ci;
      int c  = half*128 + cl;
      f16_t* hp = (f16_t*)((char*)H + mq*256 + ((((cl>>3) ^ (mq&7))<<4) | ((cl&7)<<1)));
      *hp = (f16_t)(Xb[(long)c*N_ + mq] - (float)*hp);
    }
    __syncthreads();
    {
      const uint4* src = (const uint4*)H;
      for(int i2=t;i2<1024;i2+=256){
        int row = i2>>4, slot = i2&15;
        dstb[row*32 + half*16 + slot] = src[(i2 & ~15) | (slot ^ (row&7))];
      }
    }
    __syncthreads();
  }
  #undef STAGE
}

// ---------------------------------------------------------------------------
// h1[b][o][m] = Wt @ h0 + bt (2-term: Wt hi+lo), fp16 out + BN partial sums.
// 1-D grid 2048, XCD swizzle.
__global__ __launch_bounds__(256) void k_wt_bn(
    const f16_t* __restrict__ WtS, const f16_t* __restrict__ h0T,
    const float* __restrict__ bt,
    f16_t* __restrict__ h1, float* __restrict__ bnacc)
{
  int i = blockIdx.x;
  int b = swz_b(i);
  int r = i>>4;
  int o0 = (r&3)*64, m0 = (r>>2)*64;
  int t=threadIdx.x, w=t>>6, l=t&63, lr=l&15, lg=l>>4;
  const f16_t* Arow = WtS + (long)(o0 + w*16 + lr)*512;
  const f16_t* Bb = h0T + (long)b*N_*C_;
  f32x4 acc[4];
  #pragma unroll
  for(int i2=0;i2<4;i2++) acc[i2] = fzero();
  for(int k=0;k<C_;k+=32){
    f16x8 afh = ldg8(Arow + k + lg*8);
    f16x8 afl = ldg8(Arow + 256 + k + lg*8);
    #pragma unroll
    for(int ms=0;ms<4;ms++){
      f16x8 bf_ = ldg8(Bb + (long)(m0 + ms*16 + lr)*C_ + k + lg*8);
      acc[ms] = mfma16(afh, bf_, acc[ms]);
      acc[ms] = mfma16(afl, bf_, acc[ms]);
    }
  }
  float s1[4]={0.f,0.f,0.f,0.f}, s2v[4]={0.f,0.f,0.f,0.f};
  f16_t* h1b = h1 + (long)b*C_*N_;
  #pragma unroll
  for(int j=0;j<4;j++){
    int o = o0 + w*16 + lg*4 + j;
    float bias = bt[o];
    #pragma unroll
    for(int ms=0;ms<4;ms++){
      float v = acc[ms][j] + bias;
      h1b[(long)o*N_ + m0 + ms*16 + lr] = (f16_t)v;
      s1[j] += v; s2v[j] += v*v;
    }
  }
  #pragma unroll
  for(int off=1; off<16; off<<=1){
    #pragma unroll
    for(int j=0;j<4;j++){ s1[j]+=__shfl_xor(s1[j],off,64); s2v[j]+=__shfl_xor(s2v[j],off,64); }
  }
  if(lr==0){
    #pragma unroll
    for(int j=0;j<4;j++){
      int o = o0 + w*16 + lg*4 + j;
      atomicAdd(&bnacc[o], s1[j]);
      atomicAdd(&bnacc[256+o], s2v[j]);
    }
  }
}

// BN finalize -> scale/shift
__global__ void k_bnfin(const float* __restrict__ bnacc, const float* __restrict__ gamma,
                        const float* __restrict__ beta, float* __restrict__ scsh){
  int o = threadIdx.x;
  float mean = bnacc[o] * (1.f/32768.f);
  float var  = bnacc[256+o] * (1.f/32768.f) - mean*mean;
  float sc = gamma[o] * rsqrtf(var + 1e-5f);
  scsh[o] = sc;
  scsh[256+o] = beta[o] - mean*sc;
}

// out = X + relu(h1*sc + sh); writes one 256-channel half of d_out. 8 elems/thr.
__global__ void k_out(const f16_t* __restrict__ h1, const float* __restrict__ X, long xbstride,
                      const float* __restrict__ scsh, float* __restrict__ out, long ocoff){
  long i = (long)blockIdx.x*256 + threadIdx.x;  // 1,048,576 threads
  long e = i*8;
  int b = (int)(e >> 19);
  int rem = (int)(e & 524287);                  // c*2048 + m
  int c = rem >> 11;
  f16x8 hv = *(const f16x8*)(h1 + e);
  const float* xb = X + (long)b*xbstride + rem;
  float4 xr0 = *(const float4*)xb;
  float4 xr1 = *(const float4*)(xb + 4);
  float sc = scsh[c], sh = scsh[256+c];
  float4 o0, o1;
  o0.x = xr0.x + fmaxf(fmaf((float)hv[0], sc, sh), 0.f);
  o0.y = xr0.y + fmaxf(fmaf((float)hv[1], sc, sh), 0.f);
  o0.z = xr0.z + fmaxf(fmaf((float)hv[2], sc, sh), 0.f);
  o0.w = xr0.w + fmaxf(fmaf((float)hv[3], sc, sh), 0.f);
  o1.x = xr1.x + fmaxf(fmaf((float)hv[4], sc, sh), 0.f);
  o1.y = xr1.y + fmaxf(fmaf((float)hv[5], sc, sh), 0.f);
  o1.z = xr1.z + fmaxf(fmaf((float)hv[6], sc, sh), 0.f);
  o1.w = xr1.w + fmaxf(fmaf((float)hv[7], sc, sh), 0.f);
  float* ob = out + (long)b*(512L*N_) + ocoff + rem;
  *(float4*)ob       = o0;
  *(float4*)(ob + 4) = o1;
}

// ---------------------------------------------------------------------------
extern "C" void kernel_launch(void* const* d_in, const int* in_sizes, int n_in,
                              void* d_out, int out_size, void* d_ws, size_t ws_size,
                              hipStream_t stream){
  (void)in_sizes; (void)n_in; (void)out_size; (void)ws_size;
  const float* x = (const float*)d_in[0];
  const float *Wf[2][4], *bv[2], *bt[2], *gm[2], *bb[2];
  for(int l=0;l<2;l++){
    int base = 1 + l*8;
    Wf[l][0]=(const float*)d_in[base+0];  // Wq
    Wf[l][1]=(const float*)d_in[base+1];  // Wk
    Wf[l][2]=(const float*)d_in[base+2];  // Wv
    bv[l]   =(const float*)d_in[base+3];
    Wf[l][3]=(const float*)d_in[base+4];  // Wt
    bt[l]   =(const float*)d_in[base+5];
    gm[l]   =(const float*)d_in[base+6];
    bb[l]   =(const float*)d_in[base+7];
  }
  char* ws = (char*)d_ws;
  size_t off = 0;
  auto alloc = [&](size_t bytes){ size_t o = off; off += (bytes + 255) & ~(size_t)255; return o; };
  size_t oXt = alloc((size_t)B_*N_*512*2);     // fp16 split x^T
  size_t oXq = alloc((size_t)B_*N_*256*2);     // fp16 split q [n][256]
  size_t oXk = alloc((size_t)B_*N_*256*2);     // fp16 split k [m][256]
  size_t oXv = alloc((size_t)B_*C_*N_*2);      // fp16 v [c][n]
  size_t oH0 = alloc((size_t)B_*N_*C_*2);      // fp16 h0^T [m][c]
  size_t oRo = alloc((size_t)B_*N_*4);         // f32 rowoff
  size_t oBn = alloc(2*512*4);                 // BN accum per layer
  size_t oSc = alloc(2*512*4);                 // BN scale/shift per layer
  size_t oW  = alloc((size_t)786432*2);        // fp16 split weights

  hipMemsetAsync(ws + oBn, 0, 2*512*4, stream);
  k_wconv<<<1536,256,0,stream>>>(Wf[0][0],Wf[0][1],Wf[0][2],Wf[0][3],
                                 Wf[1][0],Wf[1][1],Wf[1][2],Wf[1][3],
                                 (f16_t*)(ws+oW));
  float* dout = (float*)d_out;
  f16_t* H1 = (f16_t*)(ws + oXq);              // aliases Xq (dead when used)
  for(int l=0;l<2;l++){
    const float* Xl = l ? dout : x;
    long xbs = l ? 512L*N_ : 256L*N_;
    const f16_t* WqS = (const f16_t*)(ws+oW) + (size_t)l*393216;
    const f16_t* WkS = WqS + 65536;
    const f16_t* WvS = WqS + 131072;
    const f16_t* WtS = WqS + 262144;
    f16_t* XtS = (f16_t*)(ws+oXt);
    f16_t* Xq  = (f16_t*)(ws+oXq);
    f16_t* Xk  = (f16_t*)(ws+oXk);
    f16_t* Xv  = (f16_t*)(ws+oXv);
    f16_t* H0  = (f16_t*)(ws+oH0);
    float* Ro  = (float*)(ws+oRo);
    float* Bn  = (float*)(ws+oBn) + l*512;
    float* Sc  = (float*)(ws+oSc) + l*512;

    k_transpose<<<dim3(B_, N_/32, C_/64),256,0,stream>>>(Xl, xbs, XtS);
    k_gemm3<5,1,0><<<1024,256,0,stream>>>(XtS, (long)N_*512, WqS, 0L,
                                          Xq, 256, (long)N_*256, nullptr);
    k_gemm3<5,1,0><<<1024,256,0,stream>>>(XtS, (long)N_*512, WkS, 0L,
                                          Xk, 256, (long)N_*256, nullptr);
    k_gemm3<2,0,1><<<2048,256,0,stream>>>(WvS, 0L, XtS, (long)N_*512,
                                          Xv, N_, (long)C_*N_, bv[l]);
    k_rowstats<<<512,256,32768,stream>>>(Xq, Xk, Ro);
    k_apply<<<512,256,73728,stream>>>(Xq, Xk, Xv, Ro, Xl, xbs, H0);
    k_wt_bn<<<2048,256,0,stream>>>(WtS, H0, bt[l], H1, Bn);
    k_bnfin<<<1,256,0,stream>>>(Bn, gm[l], bb[l], Sc);
    k_out<<<4096,256,0,stream>>>(H1, Xl, xbs, Sc, dout, (long)l*C_*N_);
  }
}